// Round 1
// baseline (230.635 us; speedup 1.0000x reference)
//
#include <hip/hip_runtime.h>

// GQA attention forward: B=2,T=2048,D=1024,H=16,HKV=4,DH=64
// Pipeline: cvt(f32->bf16) -> GEMM(QKV) -> RoPE/pack -> flash attn -> GEMM(out)
// All matmuls via v_mfma_f32_16x16x32_bf16 (f32 accum).

typedef short bf16x8 __attribute__((ext_vector_type(8)));   // 8 bf16 in 4 VGPRs
typedef float f32x4 __attribute__((ext_vector_type(4)));

__device__ __forceinline__ unsigned short f2bf(float f) {
  unsigned u = __float_as_uint(f);
  u += 0x7fffu + ((u >> 16) & 1u);          // RNE (inputs finite)
  return (unsigned short)(u >> 16);
}

// ---------------- f32 -> bf16 convert, 4 elems/thread ----------------
__global__ __launch_bounds__(256) void cvt_kernel(const float* __restrict__ src,
                                                  unsigned short* __restrict__ dst,
                                                  int n4) {
  int i = blockIdx.x * blockDim.x + threadIdx.x;
  if (i >= n4) return;
  float4 v = reinterpret_cast<const float4*>(src)[i];
  ushort4 o;
  o.x = f2bf(v.x); o.y = f2bf(v.y); o.z = f2bf(v.z); o.w = f2bf(v.w);
  reinterpret_cast<ushort4*>(dst)[i] = o;
}

// ---------------- bf16 GEMM, C = A * B^T (both row-major-K) ----------------
// 128x128 tile, BK=32, 4 waves (2x2), each wave 64x64 = 4x4 MFMA frags.
__global__ __launch_bounds__(256) void gemm_bt(const unsigned short* __restrict__ A,
                                               const unsigned short* __restrict__ B,
                                               float* __restrict__ C,
                                               int M, int N, int K) {
  __shared__ unsigned short As[128][40];   // pad 32->40: 80B rows, 16B-aligned, ~2-way banks
  __shared__ unsigned short Bs[128][40];
  const int tid  = threadIdx.x;
  const int lane = tid & 63, wave = tid >> 6;
  const int wr = wave >> 1, wc = wave & 1;
  const int m0 = blockIdx.y * 128, n0 = blockIdx.x * 128;
  const int fr = lane & 15, k8 = (lane >> 4) * 8;
  const int sr = tid >> 1, sc = (tid & 1) * 16;   // stage: row, k-half
  f32x4 acc[4][4] = {};
  for (int kt = 0; kt < K; kt += 32) {
    __syncthreads();
    const unsigned short* ag = A + (size_t)(m0 + sr) * K + kt + sc;
    const unsigned short* bg = B + (size_t)(n0 + sr) * K + kt + sc;
    bf16x8 a0 = *(const bf16x8*)ag;
    bf16x8 a1 = *(const bf16x8*)(ag + 8);
    bf16x8 b0 = *(const bf16x8*)bg;
    bf16x8 b1 = *(const bf16x8*)(bg + 8);
    *(bf16x8*)&As[sr][sc]     = a0;
    *(bf16x8*)&As[sr][sc + 8] = a1;
    *(bf16x8*)&Bs[sr][sc]     = b0;
    *(bf16x8*)&Bs[sr][sc + 8] = b1;
    __syncthreads();
    bf16x8 af[4], bf[4];
#pragma unroll
    for (int i = 0; i < 4; ++i) af[i] = *(const bf16x8*)&As[wr*64 + i*16 + fr][k8];
#pragma unroll
    for (int i = 0; i < 4; ++i) bf[i] = *(const bf16x8*)&Bs[wc*64 + i*16 + fr][k8];
#pragma unroll
    for (int mi = 0; mi < 4; ++mi)
#pragma unroll
      for (int ni = 0; ni < 4; ++ni)
        acc[mi][ni] = __builtin_amdgcn_mfma_f32_16x16x32_bf16(af[mi], bf[ni], acc[mi][ni], 0, 0, 0);
  }
#pragma unroll
  for (int mi = 0; mi < 4; ++mi)
#pragma unroll
    for (int ni = 0; ni < 4; ++ni)
#pragma unroll
      for (int j = 0; j < 4; ++j) {
        int row = m0 + wr*64 + mi*16 + (lane >> 4)*4 + j;   // C/D: row=(lane>>4)*4+reg
        int col = n0 + wc*64 + ni*16 + fr;                  //       col=lane&15
        C[(size_t)row * N + col] = acc[mi][ni][j];
      }
}

// ---------------- RoPE + repack to per-head bf16 Q/K/V ----------------
// qkv: [4096][1536] f32 (cols 0-1023 Q, 1024-1279 K, 1280-1535 V)
// Qb: [B][H][T][64], Kb/Vb: [B][HKV][T][64]
__global__ __launch_bounds__(256) void rope_pack(const float* __restrict__ qkv,
                                                 const float* __restrict__ rc,
                                                 const float* __restrict__ rs,
                                                 unsigned short* __restrict__ Qb,
                                                 unsigned short* __restrict__ Kb,
                                                 unsigned short* __restrict__ Vb) {
  int tid = blockIdx.x * blockDim.x + threadIdx.x;   // over 4096*1536
  int col = tid % 1536;
  int m   = tid / 1536;
  int b = m >> 11, t = m & 2047;
  float v = qkv[(size_t)m * 1536 + col];
  int d = col & 63;
  if (col < 1280) {   // rope on q and k
    float cs = rc[t*64 + d], sn = rs[t*64 + d];
    float partner = qkv[(size_t)m*1536 + ((d < 32) ? col + 32 : col - 32)];
    float rot = (d < 32) ? -partner : partner;
    v = v * cs + rot * sn;
  }
  unsigned short o = f2bf(v);
  if (col < 1024) {
    int h = col >> 6;
    Qb[((size_t)((b*16 + h)*2048 + t) << 6) + d] = o;
  } else if (col < 1280) {
    int kh = (col - 1024) >> 6;
    Kb[((size_t)((b*4 + kh)*2048 + t) << 6) + d] = o;
  } else {
    int vh = (col - 1280) >> 6;
    Vb[((size_t)((b*4 + vh)*2048 + t) << 6) + d] = o;
  }
}

// ---------------- flash attention, causal, GQA ----------------
// grid (T/64, B*H), 256 thr = 4 waves; wave w owns q rows [qt*64+16w, +16).
// KV tile 64. QK^T and PV via 16x16x32 bf16 MFMA; online softmax.
__global__ __launch_bounds__(256) void attn_kernel(const unsigned short* __restrict__ Qb,
                                                   const unsigned short* __restrict__ Kb,
                                                   const unsigned short* __restrict__ Vb,
                                                   unsigned short* __restrict__ Yb) {
  __shared__ unsigned short Ks[64][72];      // K tile [kv][d], padded (2-way banks)
  __shared__ unsigned short Vt[64][72];      // V^T tile [d][kv]
  __shared__ unsigned short Pw[4][16][72];   // per-wave P [q][kv]
  const int qt = blockIdx.x, bh = blockIdx.y;
  const int b = bh >> 4, h = bh & 15, kvh = h >> 2;
  const int tid = threadIdx.x;
  const int wave = tid >> 6, lane = tid & 63;
  const int fr = lane & 15, k8 = (lane >> 4) * 8;
  const unsigned short* Qp = Qb + ((size_t)((b*16 + h)*2048 + qt*64)) * 64;
  const unsigned short* Kp = Kb + ((size_t)((b*4 + kvh)*2048)) * 64;
  const unsigned short* Vp = Vb + ((size_t)((b*4 + kvh)*2048)) * 64;
  // Q fragments in registers (A-operand: row=lane&15, k=(lane>>4)*8+i)
  bf16x8 qf0 = *(const bf16x8*)(Qp + (wave*16 + fr)*64 + k8);
  bf16x8 qf1 = *(const bf16x8*)(Qp + (wave*16 + fr)*64 + 32 + k8);
  float mrow[4] = {-3.0e38f, -3.0e38f, -3.0e38f, -3.0e38f};
  float lrow[4] = {0.f, 0.f, 0.f, 0.f};
  f32x4 acc[4] = {};
  const int qgb = qt*64 + wave*16 + (lane >> 4) * 4;   // + r = global q row
  const int kv_end = (qt + 1) * 64;                    // causal block limit
  for (int kv0 = 0; kv0 < kv_end; kv0 += 64) {
    __syncthreads();
    // stage K [64][64] and V^T [64][64]; 2 chunks of 8 bf16 per thread
#pragma unroll
    for (int j = 0; j < 2; ++j) {
      int chunk = tid * 2 + j;              // 0..511
      int kr = chunk >> 3, kc = (chunk & 7) * 8;
      *(bf16x8*)&Ks[kr][kc] = *(const bf16x8*)(Kp + (size_t)(kv0 + kr)*64 + kc);
      union { bf16x8 v; unsigned short u[8]; } vv;
      vv.v = *(const bf16x8*)(Vp + (size_t)(kv0 + kr)*64 + kc);
#pragma unroll
      for (int i = 0; i < 8; ++i) Vt[kc + i][kr] = vv.u[i];   // transpose
    }
    __syncthreads();
    // QK^T: 4 kv sub-tiles x 2 k-chunks
    f32x4 s[4] = {};
#pragma unroll
    for (int n = 0; n < 4; ++n) {
      bf16x8 kf0 = *(const bf16x8*)&Ks[n*16 + fr][k8];
      s[n] = __builtin_amdgcn_mfma_f32_16x16x32_bf16(qf0, kf0, s[n], 0, 0, 0);
      bf16x8 kf1 = *(const bf16x8*)&Ks[n*16 + fr][32 + k8];
      s[n] = __builtin_amdgcn_mfma_f32_16x16x32_bf16(qf1, kf1, s[n], 0, 0, 0);
    }
    // online softmax per q-row r (row values live in 16 lanes of same group)
#pragma unroll
    for (int r = 0; r < 4; ++r) {
      const int qg = qgb + r;
      float tm = -3.0e38f;
      float sv[4];
#pragma unroll
      for (int n = 0; n < 4; ++n) {
        float x = s[n][r] * 0.125f;
        if (kv0 + n*16 + fr > qg) x -= 1.0e9f;   // causal mask (matches ref -1e9)
        sv[n] = x;
        tm = fmaxf(tm, x);
      }
#pragma unroll
      for (int off = 1; off < 16; off <<= 1)
        tm = fmaxf(tm, __shfl_xor(tm, off, 16));
      float mn    = fmaxf(mrow[r], tm);
      float alpha = __expf(mrow[r] - mn);
      mrow[r] = mn;
      float rsum = 0.f;
#pragma unroll
      for (int n = 0; n < 4; ++n) {
        float p = __expf(sv[n] - mn);
        rsum += p;
        Pw[wave][(lane >> 4)*4 + r][n*16 + fr] = f2bf(p);
      }
#pragma unroll
      for (int off = 1; off < 16; off <<= 1)
        rsum += __shfl_xor(rsum, off, 16);
      lrow[r] = lrow[r] * alpha + rsum;
#pragma unroll
      for (int dt = 0; dt < 4; ++dt) acc[dt][r] *= alpha;
    }
    // PV: A = P (row=q, k=kv), B = V^T rows (col=d, k=kv). Same-wave LDS RAW:
    // DS ops execute in order per wave; compiler inserts lgkmcnt waits.
#pragma unroll
    for (int c = 0; c < 2; ++c) {
      bf16x8 pa = *(const bf16x8*)&Pw[wave][fr][c*32 + k8];
#pragma unroll
      for (int dt = 0; dt < 4; ++dt) {
        bf16x8 vf = *(const bf16x8*)&Vt[dt*16 + fr][c*32 + k8];
        acc[dt] = __builtin_amdgcn_mfma_f32_16x16x32_bf16(pa, vf, acc[dt], 0, 0, 0);
      }
    }
  }
  // epilogue: y = acc / l -> Yb[b][t][h*64+d] (bf16, row-major for out-proj GEMM)
#pragma unroll
  for (int r = 0; r < 4; ++r) {
    const int t = qgb + r;
    float inv = 1.0f / lrow[r];
#pragma unroll
    for (int dt = 0; dt < 4; ++dt) {
      size_t idx = ((size_t)(b*2048 + t) << 10) + h*64 + dt*16 + fr;
      Yb[idx] = f2bf(acc[dt][r] * inv);
    }
  }
}

extern "C" void kernel_launch(void* const* d_in, const int* in_sizes, int n_in,
                              void* d_out, int out_size, void* d_ws, size_t ws_size,
                              hipStream_t stream) {
  const float* x  = (const float*)d_in[0];
  const float* rc = (const float*)d_in[1];
  const float* rs = (const float*)d_in[2];
  // d_in[3] = attn_mask: pure causal -1e9, implemented analytically
  const float* Wq = (const float*)d_in[4];
  const float* Wk = (const float*)d_in[5];
  const float* Wv = (const float*)d_in[6];
  const float* Wo = (const float*)d_in[7];
  float* out = (float*)d_out;

  char* ws = (char*)d_ws;
  unsigned short* xb   = (unsigned short*)(ws);               // 4096x1024 bf16  (8 MB)
  unsigned short* Wcat = (unsigned short*)(ws + 8388608);     // 1536x1024 bf16  (3 MB)
  unsigned short* Wob  = (unsigned short*)(ws + 11534336);    // 1024x1024 bf16  (2 MB)
  float*          qkv  = (float*)(ws + 13631488);             // 4096x1536 f32   (24 MB)
  unsigned short* Qb   = (unsigned short*)(ws + 38797312);    // 2x16x2048x64    (8 MB)
  unsigned short* Kb   = (unsigned short*)(ws + 47185920);    // 2x4x2048x64     (2 MB)
  unsigned short* Vb   = (unsigned short*)(ws + 49283072);    // 2x4x2048x64     (2 MB)
  unsigned short* Yb   = (unsigned short*)(ws + 51380224);    // 4096x1024 bf16  (8 MB)

  cvt_kernel<<<4096, 256, 0, stream>>>(x,  xb,             1048576);
  cvt_kernel<<<1024, 256, 0, stream>>>(Wq, Wcat,            262144);
  cvt_kernel<<<256,  256, 0, stream>>>(Wk, Wcat + 1048576,   65536);
  cvt_kernel<<<256,  256, 0, stream>>>(Wv, Wcat + 1310720,   65536);
  cvt_kernel<<<1024, 256, 0, stream>>>(Wo, Wob,             262144);

  gemm_bt<<<dim3(12, 32), 256, 0, stream>>>(xb, Wcat, qkv, 4096, 1536, 1024);
  rope_pack<<<24576, 256, 0, stream>>>(qkv, rc, rs, Qb, Kb, Vb);
  attn_kernel<<<dim3(32, 32), 256, 0, stream>>>(Qb, Kb, Vb, Yb);
  gemm_bt<<<dim3(8, 32), 256, 0, stream>>>(Yb, Wob, out, 4096, 1024, 1024);
}

// Round 2
// 180.040 us; speedup vs baseline: 1.2810x; 1.2810x over previous
//
#include <hip/hip_runtime.h>

// GQA attention forward: B=2,T=2048,D=1024,H=16,HKV=4,DH=64
// Pipeline: cvt(f32->bf16) -> GEMM(QKV) -> RoPE/pack -> flash attn -> GEMM(out)
// All matmuls via v_mfma_f32_16x16x32_bf16 (f32 accum).
// R2: attention rebalanced (paired q-tiles {p,31-p}, shared K/V staging),
//     V pre-transposed in rope_pack (kills in-kernel transpose bank conflicts),
//     softmax in exp2 domain, mask only on diagonal tiles.

typedef short bf16x8 __attribute__((ext_vector_type(8)));   // 8 bf16 in 4 VGPRs
typedef float f32x4 __attribute__((ext_vector_type(4)));

__device__ __forceinline__ unsigned short f2bf(float f) {
  unsigned u = __float_as_uint(f);
  u += 0x7fffu + ((u >> 16) & 1u);          // RNE (inputs finite)
  return (unsigned short)(u >> 16);
}

__device__ __forceinline__ float fexp2(float x) {
#if __has_builtin(__builtin_amdgcn_exp2f)
  return __builtin_amdgcn_exp2f(x);
#else
  return __expf(x * 0.69314718056f);
#endif
}

// ---------------- f32 -> bf16 convert, 4 elems/thread ----------------
__global__ __launch_bounds__(256) void cvt_kernel(const float* __restrict__ src,
                                                  unsigned short* __restrict__ dst,
                                                  int n4) {
  int i = blockIdx.x * blockDim.x + threadIdx.x;
  if (i >= n4) return;
  float4 v = reinterpret_cast<const float4*>(src)[i];
  ushort4 o;
  o.x = f2bf(v.x); o.y = f2bf(v.y); o.z = f2bf(v.z); o.w = f2bf(v.w);
  reinterpret_cast<ushort4*>(dst)[i] = o;
}

// ---------------- bf16 GEMM, C = A * B^T (both row-major-K) ----------------
// 128x128 tile, BK=32, 4 waves (2x2), each wave 64x64 = 4x4 MFMA frags.
__global__ __launch_bounds__(256) void gemm_bt(const unsigned short* __restrict__ A,
                                               const unsigned short* __restrict__ B,
                                               float* __restrict__ C,
                                               int M, int N, int K) {
  __shared__ unsigned short As[128][40];
  __shared__ unsigned short Bs[128][40];
  const int tid  = threadIdx.x;
  const int lane = tid & 63, wave = tid >> 6;
  const int wr = wave >> 1, wc = wave & 1;
  const int m0 = blockIdx.y * 128, n0 = blockIdx.x * 128;
  const int fr = lane & 15, k8 = (lane >> 4) * 8;
  const int sr = tid >> 1, sc = (tid & 1) * 16;
  f32x4 acc[4][4] = {};
  for (int kt = 0; kt < K; kt += 32) {
    __syncthreads();
    const unsigned short* ag = A + (size_t)(m0 + sr) * K + kt + sc;
    const unsigned short* bg = B + (size_t)(n0 + sr) * K + kt + sc;
    bf16x8 a0 = *(const bf16x8*)ag;
    bf16x8 a1 = *(const bf16x8*)(ag + 8);
    bf16x8 b0 = *(const bf16x8*)bg;
    bf16x8 b1 = *(const bf16x8*)(bg + 8);
    *(bf16x8*)&As[sr][sc]     = a0;
    *(bf16x8*)&As[sr][sc + 8] = a1;
    *(bf16x8*)&Bs[sr][sc]     = b0;
    *(bf16x8*)&Bs[sr][sc + 8] = b1;
    __syncthreads();
    bf16x8 af[4], bf[4];
#pragma unroll
    for (int i = 0; i < 4; ++i) af[i] = *(const bf16x8*)&As[wr*64 + i*16 + fr][k8];
#pragma unroll
    for (int i = 0; i < 4; ++i) bf[i] = *(const bf16x8*)&Bs[wc*64 + i*16 + fr][k8];
#pragma unroll
    for (int mi = 0; mi < 4; ++mi)
#pragma unroll
      for (int ni = 0; ni < 4; ++ni)
        acc[mi][ni] = __builtin_amdgcn_mfma_f32_16x16x32_bf16(af[mi], bf[ni], acc[mi][ni], 0, 0, 0);
  }
#pragma unroll
  for (int mi = 0; mi < 4; ++mi)
#pragma unroll
    for (int ni = 0; ni < 4; ++ni)
#pragma unroll
      for (int j = 0; j < 4; ++j) {
        int row = m0 + wr*64 + mi*16 + (lane >> 4)*4 + j;
        int col = n0 + wc*64 + ni*16 + fr;
        C[(size_t)row * N + col] = acc[mi][ni][j];
      }
}

// ---------------- RoPE + repack to per-head bf16 Q/K/V ----------------
// qkv: [4096][1536] f32 (cols 0-1023 Q, 1024-1279 K, 1280-1535 V)
// Qb: [B][H][T][64], Kb: [B][HKV][T][64], Vb TRANSPOSED: [B][HKV][64][T]
__global__ __launch_bounds__(256) void rope_pack(const float* __restrict__ qkv,
                                                 const float* __restrict__ rc,
                                                 const float* __restrict__ rs,
                                                 unsigned short* __restrict__ Qb,
                                                 unsigned short* __restrict__ Kb,
                                                 unsigned short* __restrict__ Vb) {
  int tid = blockIdx.x * blockDim.x + threadIdx.x;   // over 4096*1536
  int col = tid % 1536;
  int m   = tid / 1536;
  int b = m >> 11, t = m & 2047;
  float v = qkv[(size_t)m * 1536 + col];
  int d = col & 63;
  if (col < 1280) {   // rope on q and k
    float cs = rc[t*64 + d], sn = rs[t*64 + d];
    float partner = qkv[(size_t)m*1536 + ((d < 32) ? col + 32 : col - 32)];
    float rot = (d < 32) ? -partner : partner;
    v = v * cs + rot * sn;
  }
  unsigned short o = f2bf(v);
  if (col < 1024) {
    int h = col >> 6;
    Qb[((size_t)((b*16 + h)*2048 + t) << 6) + d] = o;
  } else if (col < 1280) {
    int kh = (col - 1024) >> 6;
    Kb[((size_t)((b*4 + kh)*2048 + t) << 6) + d] = o;
  } else {
    int vh = (col - 1280) >> 6;
    Vb[((size_t)(b*4 + vh)*64 + d)*2048 + t] = o;   // V^T layout [d][T]
  }
}

// ---------------- flash attention, causal, GQA, paired q-tiles ----------------
// grid (16, B*H): block p handles q-tiles qtA=31-p (always) and qtB=p
// (while kv tile kt <= p). K/V staged once per tile, shared by both.
// 256 thr = 4 waves; wave w owns q rows [qt*64+16w, +16) of each q-tile.
__global__ __launch_bounds__(256) void attn_kernel(const unsigned short* __restrict__ Qb,
                                                   const unsigned short* __restrict__ Kb,
                                                   const unsigned short* __restrict__ Vb,
                                                   unsigned short* __restrict__ Yb) {
  __shared__ unsigned short Ks[64][72];      // K tile [kv][d]
  __shared__ unsigned short Vt[64][72];      // V^T tile [d][kv] (direct from Vb)
  __shared__ unsigned short PA[4][16][72];   // per-wave P for q-tile A
  __shared__ unsigned short PB[4][16][72];   // per-wave P for q-tile B
  const int p = blockIdx.x, bh = blockIdx.y;
  const int b = bh >> 4, h = bh & 15, kvh = h >> 2;
  const int qtA = 31 - p, qtB = p;
  const int nkv = qtA + 1;
  const int tid = threadIdx.x;
  const int wave = tid >> 6, lane = tid & 63;
  const int fr = lane & 15, k8 = (lane >> 4) * 8;
  const unsigned short* Kp = Kb + ((size_t)(b*4 + kvh)*2048) * 64;
  const unsigned short* Vp = Vb + ((size_t)(b*4 + kvh)*64) * 2048;
  const unsigned short* QpA = Qb + ((size_t)((b*16 + h)*2048 + qtA*64)) * 64;
  const unsigned short* QpB = Qb + ((size_t)((b*16 + h)*2048 + qtB*64)) * 64;
  // Q fragments in registers (A-operand: row=lane&15, k=(lane>>4)*8+i)
  bf16x8 qfA0 = *(const bf16x8*)(QpA + (wave*16 + fr)*64 + k8);
  bf16x8 qfA1 = *(const bf16x8*)(QpA + (wave*16 + fr)*64 + 32 + k8);
  bf16x8 qfB0 = *(const bf16x8*)(QpB + (wave*16 + fr)*64 + k8);
  bf16x8 qfB1 = *(const bf16x8*)(QpB + (wave*16 + fr)*64 + 32 + k8);
  float mA[4] = {-3.0e38f,-3.0e38f,-3.0e38f,-3.0e38f}, lA[4] = {0,0,0,0};
  float mB[4] = {-3.0e38f,-3.0e38f,-3.0e38f,-3.0e38f}, lB[4] = {0,0,0,0};
  f32x4 accA[4] = {}, accB[4] = {};
  const int rgrp = (lane >> 4) * 4;
  const int qgbA = qtA*64 + wave*16 + rgrp;
  const int qgbB = qtB*64 + wave*16 + rgrp;
  // softmax scale: (1/sqrt(64)) * log2(e), work in exp2 domain
  const float SCL = 0.125f * 1.44269504f;

  for (int kt = 0; kt < nkv; ++kt) {
    const int kv0 = kt * 64;
    const bool actB = (kt <= qtB);
    __syncthreads();
#pragma unroll
    for (int j = 0; j < 2; ++j) {
      int chunk = j*256 + tid;              // 0..511
      int r = chunk >> 3, c8 = (chunk & 7) * 8;
      *(bf16x8*)&Ks[r][c8] = *(const bf16x8*)(Kp + (size_t)(kv0 + r)*64 + c8);
      *(bf16x8*)&Vt[r][c8] = *(const bf16x8*)(Vp + (size_t)r*2048 + kv0 + c8);
    }
    __syncthreads();
    // QK^T: shared K fragments feed both q-tiles
    f32x4 sA[4] = {}, sB[4] = {};
#pragma unroll
    for (int n = 0; n < 4; ++n) {
      bf16x8 kf0 = *(const bf16x8*)&Ks[n*16 + fr][k8];
      sA[n] = __builtin_amdgcn_mfma_f32_16x16x32_bf16(qfA0, kf0, sA[n], 0, 0, 0);
      if (actB) sB[n] = __builtin_amdgcn_mfma_f32_16x16x32_bf16(qfB0, kf0, sB[n], 0, 0, 0);
      bf16x8 kf1 = *(const bf16x8*)&Ks[n*16 + fr][32 + k8];
      sA[n] = __builtin_amdgcn_mfma_f32_16x16x32_bf16(qfA1, kf1, sA[n], 0, 0, 0);
      if (actB) sB[n] = __builtin_amdgcn_mfma_f32_16x16x32_bf16(qfB1, kf1, sB[n], 0, 0, 0);
    }
    // online softmax (exp2 domain); mask only on diagonal tile
    {
      const bool diag = (kt == qtA);
#pragma unroll
      for (int r = 0; r < 4; ++r) {
        const int qg = qgbA + r;
        float sv[4], tm = -3.0e38f;
#pragma unroll
        for (int n = 0; n < 4; ++n) {
          float x = sA[n][r] * SCL;
          if (diag && (kv0 + n*16 + fr > qg)) x = -3.0e38f;
          sv[n] = x; tm = fmaxf(tm, x);
        }
#pragma unroll
        for (int off = 1; off < 16; off <<= 1) tm = fmaxf(tm, __shfl_xor(tm, off, 16));
        float mn = fmaxf(mA[r], tm);
        float alpha = fexp2(mA[r] - mn);
        mA[r] = mn;
        float rsum = 0.f;
#pragma unroll
        for (int n = 0; n < 4; ++n) {
          float pp = fexp2(sv[n] - mn);
          rsum += pp;
          PA[wave][rgrp + r][n*16 + fr] = f2bf(pp);
        }
#pragma unroll
        for (int off = 1; off < 16; off <<= 1) rsum += __shfl_xor(rsum, off, 16);
        lA[r] = lA[r] * alpha + rsum;
#pragma unroll
        for (int dt = 0; dt < 4; ++dt) accA[dt][r] *= alpha;
      }
    }
    if (actB) {
      const bool diag = (kt == qtB);
#pragma unroll
      for (int r = 0; r < 4; ++r) {
        const int qg = qgbB + r;
        float sv[4], tm = -3.0e38f;
#pragma unroll
        for (int n = 0; n < 4; ++n) {
          float x = sB[n][r] * SCL;
          if (diag && (kv0 + n*16 + fr > qg)) x = -3.0e38f;
          sv[n] = x; tm = fmaxf(tm, x);
        }
#pragma unroll
        for (int off = 1; off < 16; off <<= 1) tm = fmaxf(tm, __shfl_xor(tm, off, 16));
        float mn = fmaxf(mB[r], tm);
        float alpha = fexp2(mB[r] - mn);
        mB[r] = mn;
        float rsum = 0.f;
#pragma unroll
        for (int n = 0; n < 4; ++n) {
          float pp = fexp2(sv[n] - mn);
          rsum += pp;
          PB[wave][rgrp + r][n*16 + fr] = f2bf(pp);
        }
#pragma unroll
        for (int off = 1; off < 16; off <<= 1) rsum += __shfl_xor(rsum, off, 16);
        lB[r] = lB[r] * alpha + rsum;
#pragma unroll
        for (int dt = 0; dt < 4; ++dt) accB[dt][r] *= alpha;
      }
    }
    // PV: shared V fragments feed both q-tiles (same-wave LDS RAW on PA/PB)
#pragma unroll
    for (int c = 0; c < 2; ++c) {
      bf16x8 paA = *(const bf16x8*)&PA[wave][fr][c*32 + k8];
      bf16x8 paB;
      if (actB) paB = *(const bf16x8*)&PB[wave][fr][c*32 + k8];
#pragma unroll
      for (int dt = 0; dt < 4; ++dt) {
        bf16x8 vf = *(const bf16x8*)&Vt[dt*16 + fr][c*32 + k8];
        accA[dt] = __builtin_amdgcn_mfma_f32_16x16x32_bf16(paA, vf, accA[dt], 0, 0, 0);
        if (actB) accB[dt] = __builtin_amdgcn_mfma_f32_16x16x32_bf16(paB, vf, accB[dt], 0, 0, 0);
      }
    }
  }
  // epilogue: y = acc / l -> Yb[b][t][h*64+d]
#pragma unroll
  for (int r = 0; r < 4; ++r) {
    const int tA = qgbA + r;
    float invA = 1.0f / lA[r];
#pragma unroll
    for (int dt = 0; dt < 4; ++dt) {
      size_t idx = ((size_t)(b*2048 + tA) << 10) + h*64 + dt*16 + fr;
      Yb[idx] = f2bf(accA[dt][r] * invA);
    }
    const int tB = qgbB + r;
    float invB = 1.0f / lB[r];
#pragma unroll
    for (int dt = 0; dt < 4; ++dt) {
      size_t idx = ((size_t)(b*2048 + tB) << 10) + h*64 + dt*16 + fr;
      Yb[idx] = f2bf(accB[dt][r] * invB);
    }
  }
}

extern "C" void kernel_launch(void* const* d_in, const int* in_sizes, int n_in,
                              void* d_out, int out_size, void* d_ws, size_t ws_size,
                              hipStream_t stream) {
  const float* x  = (const float*)d_in[0];
  const float* rc = (const float*)d_in[1];
  const float* rs = (const float*)d_in[2];
  // d_in[3] = attn_mask: pure causal -1e9, implemented analytically
  const float* Wq = (const float*)d_in[4];
  const float* Wk = (const float*)d_in[5];
  const float* Wv = (const float*)d_in[6];
  const float* Wo = (const float*)d_in[7];
  float* out = (float*)d_out;

  char* ws = (char*)d_ws;
  unsigned short* xb   = (unsigned short*)(ws);               // 4096x1024 bf16  (8 MB)
  unsigned short* Wcat = (unsigned short*)(ws + 8388608);     // 1536x1024 bf16  (3 MB)
  unsigned short* Wob  = (unsigned short*)(ws + 11534336);    // 1024x1024 bf16  (2 MB)
  float*          qkv  = (float*)(ws + 13631488);             // 4096x1536 f32   (24 MB)
  unsigned short* Qb   = (unsigned short*)(ws + 38797312);    // 2x16x2048x64    (8 MB)
  unsigned short* Kb   = (unsigned short*)(ws + 47185920);    // 2x4x2048x64     (2 MB)
  unsigned short* Vb   = (unsigned short*)(ws + 49283072);    // 2x4x64x2048 ^T  (2 MB)
  unsigned short* Yb   = (unsigned short*)(ws + 51380224);    // 4096x1024 bf16  (8 MB)

  cvt_kernel<<<4096, 256, 0, stream>>>(x,  xb,             1048576);
  cvt_kernel<<<1024, 256, 0, stream>>>(Wq, Wcat,            262144);
  cvt_kernel<<<256,  256, 0, stream>>>(Wk, Wcat + 1048576,   65536);
  cvt_kernel<<<256,  256, 0, stream>>>(Wv, Wcat + 1310720,   65536);
  cvt_kernel<<<1024, 256, 0, stream>>>(Wo, Wob,             262144);

  gemm_bt<<<dim3(12, 32), 256, 0, stream>>>(xb, Wcat, qkv, 4096, 1536, 1024);
  rope_pack<<<24576, 256, 0, stream>>>(qkv, rc, rs, Qb, Kb, Vb);
  attn_kernel<<<dim3(16, 32), 256, 0, stream>>>(Qb, Kb, Vb, Yb);
  gemm_bt<<<dim3(8, 32), 256, 0, stream>>>(Yb, Wob, out, 4096, 1024, 1024);
}

// Round 3
// 176.485 us; speedup vs baseline: 1.3068x; 1.0201x over previous
//
#include <hip/hip_runtime.h>

// GQA attention forward: B=2,T=2048,D=1024,H=16,HKV=4,DH=64
// Pipeline: cvt(f32->bf16) -> GEMM(QKV) -> RoPE/pack -> flash attn -> GEMM(out)
// R3: attn swapped-operand QK^T (lane-local softmax rows, 2 shfl/tile),
//     packed P^T in LDS (u32, stride-20, <=2-way banks), O^T accumulator;
//     gemm_bt staging via global_load_lds width=16 (m97 pattern).

typedef short bf16x8 __attribute__((ext_vector_type(8)));   // 8 bf16 in 4 VGPRs
typedef float f32x4 __attribute__((ext_vector_type(4)));

__device__ __forceinline__ unsigned short f2bf(float f) {
  unsigned u = __float_as_uint(f);
  u += 0x7fffu + ((u >> 16) & 1u);          // RNE (inputs finite)
  return (unsigned short)(u >> 16);
}

__device__ __forceinline__ float fexp2(float x) {
#if __has_builtin(__builtin_amdgcn_exp2f)
  return __builtin_amdgcn_exp2f(x);
#else
  return __expf(x * 0.69314718056f);
#endif
}

__device__ __forceinline__ void load_lds16(const void* g, void* l) {
  __builtin_amdgcn_global_load_lds(
      (const __attribute__((address_space(1))) void*)g,
      (__attribute__((address_space(3))) void*)l, 16, 0, 0);
}

// ---------------- f32 -> bf16 convert, 4 elems/thread ----------------
__global__ __launch_bounds__(256) void cvt_kernel(const float* __restrict__ src,
                                                  unsigned short* __restrict__ dst,
                                                  int n4) {
  int i = blockIdx.x * blockDim.x + threadIdx.x;
  if (i >= n4) return;
  float4 v = reinterpret_cast<const float4*>(src)[i];
  ushort4 o;
  o.x = f2bf(v.x); o.y = f2bf(v.y); o.z = f2bf(v.z); o.w = f2bf(v.w);
  reinterpret_cast<ushort4*>(dst)[i] = o;
}

// ---------------- bf16 GEMM, C = A * B^T (both row-major-K) ----------------
// 128x128 tile, BK=32, 4 waves (2x2), global_load_lds dwordx4 staging.
__global__ __launch_bounds__(256) void gemm_bt(const unsigned short* __restrict__ A,
                                               const unsigned short* __restrict__ B,
                                               float* __restrict__ C,
                                               int M, int N, int K) {
  __shared__ unsigned short As[128][32];   // linear (global_load_lds needs contiguity)
  __shared__ unsigned short Bs[128][32];
  const int tid  = threadIdx.x;
  const int lane = tid & 63, wave = tid >> 6;
  const int wr = wave >> 1, wc = wave & 1;
  const int m0 = blockIdx.y * 128, n0 = blockIdx.x * 128;
  const int fr = lane & 15, k8 = (lane >> 4) * 8;
  f32x4 acc[4][4] = {};
  for (int kt = 0; kt < K; kt += 32) {
    __syncthreads();
#pragma unroll
    for (int j = 0; j < 2; ++j) {
      // wave-uniform LDS dest (1KB span, lane i -> +16i); per-lane global src
      const int cs  = (j*4 + wave);
      const int c   = cs*64 + lane;
      const int row = c >> 2, col = (c & 3) * 8;
      load_lds16(A + (size_t)(m0 + row)*K + kt + col, (char*)&As[0][0] + (size_t)cs*1024);
      load_lds16(B + (size_t)(n0 + row)*K + kt + col, (char*)&Bs[0][0] + (size_t)cs*1024);
    }
    __syncthreads();   // drains vmcnt -> LDS writes visible
    bf16x8 af[4], bf[4];
#pragma unroll
    for (int i = 0; i < 4; ++i) af[i] = *(const bf16x8*)&As[wr*64 + i*16 + fr][k8];
#pragma unroll
    for (int i = 0; i < 4; ++i) bf[i] = *(const bf16x8*)&Bs[wc*64 + i*16 + fr][k8];
#pragma unroll
    for (int mi = 0; mi < 4; ++mi)
#pragma unroll
      for (int ni = 0; ni < 4; ++ni)
        acc[mi][ni] = __builtin_amdgcn_mfma_f32_16x16x32_bf16(af[mi], bf[ni], acc[mi][ni], 0, 0, 0);
  }
#pragma unroll
  for (int mi = 0; mi < 4; ++mi)
#pragma unroll
    for (int ni = 0; ni < 4; ++ni)
#pragma unroll
      for (int j = 0; j < 4; ++j) {
        int row = m0 + wr*64 + mi*16 + (lane >> 4)*4 + j;
        int col = n0 + wc*64 + ni*16 + fr;
        C[(size_t)row * N + col] = acc[mi][ni][j];
      }
}

// ---------------- RoPE + repack to per-head bf16 Q/K/V ----------------
// qkv: [4096][1536] f32 (cols 0-1023 Q, 1024-1279 K, 1280-1535 V)
// Qb: [B][H][T][64], Kb: [B][HKV][T][64], Vb TRANSPOSED: [B][HKV][64][T]
__global__ __launch_bounds__(256) void rope_pack(const float* __restrict__ qkv,
                                                 const float* __restrict__ rc,
                                                 const float* __restrict__ rs,
                                                 unsigned short* __restrict__ Qb,
                                                 unsigned short* __restrict__ Kb,
                                                 unsigned short* __restrict__ Vb) {
  int tid = blockIdx.x * blockDim.x + threadIdx.x;   // over 4096*1536
  int col = tid % 1536;
  int m   = tid / 1536;
  int b = m >> 11, t = m & 2047;
  float v = qkv[(size_t)m * 1536 + col];
  int d = col & 63;
  if (col < 1280) {   // rope on q and k
    float cs = rc[t*64 + d], sn = rs[t*64 + d];
    float partner = qkv[(size_t)m*1536 + ((d < 32) ? col + 32 : col - 32)];
    float rot = (d < 32) ? -partner : partner;
    v = v * cs + rot * sn;
  }
  unsigned short o = f2bf(v);
  if (col < 1024) {
    int h = col >> 6;
    Qb[((size_t)((b*16 + h)*2048 + t) << 6) + d] = o;
  } else if (col < 1280) {
    int kh = (col - 1024) >> 6;
    Kb[((size_t)((b*4 + kh)*2048 + t) << 6) + d] = o;
  } else {
    int vh = (col - 1280) >> 6;
    Vb[((size_t)(b*4 + vh)*64 + d)*2048 + t] = o;   // V^T layout [d][T]
  }
}

// ---------------- flash attention, causal, GQA, paired q-tiles ----------------
// grid (16, B*H): block p handles q-tiles qtA=31-p (always) and qtB=p (kt<=p).
// Swapped QK^T: S^T = mfma(K, Q) -> lane owns ONE q-row (q = lane&15),
// kv spread over 16 regs x 4 lane-groups. Softmax: 15 in-reg ops + 2 shfl.
// P^T packed (2xbf16 per u32) in LDS; PV: O^T = mfma(V^T, P^T).
__global__ __launch_bounds__(256) void attn_kernel(const unsigned short* __restrict__ Qb,
                                                   const unsigned short* __restrict__ Kb,
                                                   const unsigned short* __restrict__ Vb,
                                                   unsigned short* __restrict__ Yb) {
  __shared__ unsigned short Ks[64][72];      // K tile [kv][d]
  __shared__ unsigned short Vt[64][72];      // V^T tile [d][kv]
  __shared__ unsigned PpA[4][32][20];        // per-wave packed P^T [kv2][q], stride 20
  __shared__ unsigned PpB[4][32][20];
  const int p = blockIdx.x, bh = blockIdx.y;
  const int b = bh >> 4, h = bh & 15, kvh = h >> 2;
  const int qtA = 31 - p, qtB = p;
  const int nkv = qtA + 1;
  const int tid = threadIdx.x;
  const int wave = tid >> 6, lane = tid & 63;
  const int fr = lane & 15, g = lane >> 4, k8 = g * 8;
  const unsigned short* Kp = Kb + ((size_t)(b*4 + kvh)*2048) * 64;
  const unsigned short* Vp = Vb + ((size_t)(b*4 + kvh)*64) * 2048;
  const unsigned short* QpA = Qb + ((size_t)((b*16 + h)*2048 + qtA*64)) * 64;
  const unsigned short* QpB = Qb + ((size_t)((b*16 + h)*2048 + qtB*64)) * 64;
  // Q as B-operand: col=q=lane&15, k=g*8+i  (same memory fragment as A-form)
  bf16x8 qfA0 = *(const bf16x8*)(QpA + (wave*16 + fr)*64 + k8);
  bf16x8 qfA1 = *(const bf16x8*)(QpA + (wave*16 + fr)*64 + 32 + k8);
  bf16x8 qfB0 = *(const bf16x8*)(QpB + (wave*16 + fr)*64 + k8);
  bf16x8 qfB1 = *(const bf16x8*)(QpB + (wave*16 + fr)*64 + 32 + k8);
  float mA = -3.0e38f, lA = 0.f, mB = -3.0e38f, lB = 0.f;   // per-lane (one q each)
  f32x4 accA[4] = {}, accB[4] = {};                          // O^T: d=dt*16+g*4+j, q=fr
  const int qgA = qtA*64 + wave*16 + fr;   // this lane's q row (tile A)
  const int qgB = qtB*64 + wave*16 + fr;
  const float SCL = 0.125f * 1.44269504f;  // 1/sqrt(64) * log2(e)

  for (int kt = 0; kt < nkv; ++kt) {
    const int kv0 = kt * 64;
    const bool actB = (kt <= qtB);
    __syncthreads();
#pragma unroll
    for (int j = 0; j < 2; ++j) {
      int chunk = j*256 + tid;              // 0..511
      int r = chunk >> 3, c8 = (chunk & 7) * 8;
      *(bf16x8*)&Ks[r][c8] = *(const bf16x8*)(Kp + (size_t)(kv0 + r)*64 + c8);
      *(bf16x8*)&Vt[r][c8] = *(const bf16x8*)(Vp + (size_t)r*2048 + kv0 + c8);
    }
    __syncthreads();
    // QK^T swapped: sT[n] = S^T[kv=n*16+g*4+r][q=fr]
    f32x4 sA[4] = {}, sB[4] = {};
#pragma unroll
    for (int n = 0; n < 4; ++n) {
      bf16x8 kf0 = *(const bf16x8*)&Ks[n*16 + fr][k8];        // A-op: row=kv, k
      sA[n] = __builtin_amdgcn_mfma_f32_16x16x32_bf16(kf0, qfA0, sA[n], 0, 0, 0);
      if (actB) sB[n] = __builtin_amdgcn_mfma_f32_16x16x32_bf16(kf0, qfB0, sB[n], 0, 0, 0);
      bf16x8 kf1 = *(const bf16x8*)&Ks[n*16 + fr][32 + k8];
      sA[n] = __builtin_amdgcn_mfma_f32_16x16x32_bf16(kf1, qfA1, sA[n], 0, 0, 0);
      if (actB) sB[n] = __builtin_amdgcn_mfma_f32_16x16x32_bf16(kf1, qfB1, sB[n], 0, 0, 0);
    }
    // ---- softmax A (lane-local row) ----
    {
      const bool diag = (kt == qtA);
      float sv[4][4], tm = -3.0e38f;
#pragma unroll
      for (int n = 0; n < 4; ++n)
#pragma unroll
        for (int r = 0; r < 4; ++r) {
          float x = sA[n][r] * SCL;
          if (diag && (kv0 + n*16 + g*4 + r > qgA)) x = -3.0e38f;
          sv[n][r] = x; tm = fmaxf(tm, x);
        }
      tm = fmaxf(tm, __shfl_xor(tm, 16));
      tm = fmaxf(tm, __shfl_xor(tm, 32));
      float mn = fmaxf(mA, tm);
      float alpha = fexp2(mA - mn);
      mA = mn;
      float rsum = 0.f;
#pragma unroll
      for (int n = 0; n < 4; ++n)
#pragma unroll
        for (int r2 = 0; r2 < 2; ++r2) {
          float p0 = fexp2(sv[n][2*r2]   - mn);
          float p1 = fexp2(sv[n][2*r2+1] - mn);
          rsum += p0 + p1;
          PpA[wave][n*8 + g*2 + r2][fr] = (unsigned)f2bf(p0) | ((unsigned)f2bf(p1) << 16);
        }
      rsum += __shfl_xor(rsum, 16);
      rsum += __shfl_xor(rsum, 32);
      lA = lA * alpha + rsum;
#pragma unroll
      for (int dt = 0; dt < 4; ++dt) accA[dt] *= alpha;
    }
    // ---- softmax B ----
    if (actB) {
      const bool diag = (kt == qtB);
      float sv[4][4], tm = -3.0e38f;
#pragma unroll
      for (int n = 0; n < 4; ++n)
#pragma unroll
        for (int r = 0; r < 4; ++r) {
          float x = sB[n][r] * SCL;
          if (diag && (kv0 + n*16 + g*4 + r > qgB)) x = -3.0e38f;
          sv[n][r] = x; tm = fmaxf(tm, x);
        }
      tm = fmaxf(tm, __shfl_xor(tm, 16));
      tm = fmaxf(tm, __shfl_xor(tm, 32));
      float mn = fmaxf(mB, tm);
      float alpha = fexp2(mB - mn);
      mB = mn;
      float rsum = 0.f;
#pragma unroll
      for (int n = 0; n < 4; ++n)
#pragma unroll
        for (int r2 = 0; r2 < 2; ++r2) {
          float p0 = fexp2(sv[n][2*r2]   - mn);
          float p1 = fexp2(sv[n][2*r2+1] - mn);
          rsum += p0 + p1;
          PpB[wave][n*8 + g*2 + r2][fr] = (unsigned)f2bf(p0) | ((unsigned)f2bf(p1) << 16);
        }
      rsum += __shfl_xor(rsum, 16);
      rsum += __shfl_xor(rsum, 32);
      lB = lB * alpha + rsum;
#pragma unroll
      for (int dt = 0; dt < 4; ++dt) accB[dt] *= alpha;
    }
    // ---- PV: O^T += V^T * P^T (same-wave LDS RAW; DS in-order per wave) ----
#pragma unroll
    for (int c = 0; c < 2; ++c) {
      union { unsigned u[4]; bf16x8 v; } pa, pb;
#pragma unroll
      for (int i2 = 0; i2 < 4; ++i2) pa.u[i2] = PpA[wave][c*16 + g*4 + i2][fr];
      if (actB) {
#pragma unroll
        for (int i2 = 0; i2 < 4; ++i2) pb.u[i2] = PpB[wave][c*16 + g*4 + i2][fr];
      }
#pragma unroll
      for (int dt = 0; dt < 4; ++dt) {
        bf16x8 vf = *(const bf16x8*)&Vt[dt*16 + fr][c*32 + k8];   // A-op: row=d, k=kv
        accA[dt] = __builtin_amdgcn_mfma_f32_16x16x32_bf16(vf, pa.v, accA[dt], 0, 0, 0);
        if (actB) accB[dt] = __builtin_amdgcn_mfma_f32_16x16x32_bf16(vf, pb.v, accB[dt], 0, 0, 0);
      }
    }
  }
  // epilogue: lane owns q-col; y = O^T[:,q]/l -> Yb[b][t=q][h*64+d], packed u32
  {
    const float invA = 1.0f / lA;
    size_t base = ((size_t)(b*2048 + qgA) << 10) + h*64;
#pragma unroll
    for (int dt = 0; dt < 4; ++dt)
#pragma unroll
      for (int j2 = 0; j2 < 2; ++j2) {
        unsigned pk = (unsigned)f2bf(accA[dt][2*j2] * invA)
                    | ((unsigned)f2bf(accA[dt][2*j2+1] * invA) << 16);
        *(unsigned*)&Yb[base + dt*16 + g*4 + 2*j2] = pk;
      }
  }
  {
    const float invB = 1.0f / lB;
    size_t base = ((size_t)(b*2048 + qgB) << 10) + h*64;
#pragma unroll
    for (int dt = 0; dt < 4; ++dt)
#pragma unroll
      for (int j2 = 0; j2 < 2; ++j2) {
        unsigned pk = (unsigned)f2bf(accB[dt][2*j2] * invB)
                    | ((unsigned)f2bf(accB[dt][2*j2+1] * invB) << 16);
        *(unsigned*)&Yb[base + dt*16 + g*4 + 2*j2] = pk;
      }
  }
}

extern "C" void kernel_launch(void* const* d_in, const int* in_sizes, int n_in,
                              void* d_out, int out_size, void* d_ws, size_t ws_size,
                              hipStream_t stream) {
  const float* x  = (const float*)d_in[0];
  const float* rc = (const float*)d_in[1];
  const float* rs = (const float*)d_in[2];
  // d_in[3] = attn_mask: pure causal -1e9, implemented analytically
  const float* Wq = (const float*)d_in[4];
  const float* Wk = (const float*)d_in[5];
  const float* Wv = (const float*)d_in[6];
  const float* Wo = (const float*)d_in[7];
  float* out = (float*)d_out;

  char* ws = (char*)d_ws;
  unsigned short* xb   = (unsigned short*)(ws);               // 4096x1024 bf16  (8 MB)
  unsigned short* Wcat = (unsigned short*)(ws + 8388608);     // 1536x1024 bf16  (3 MB)
  unsigned short* Wob  = (unsigned short*)(ws + 11534336);    // 1024x1024 bf16  (2 MB)
  float*          qkv  = (float*)(ws + 13631488);             // 4096x1536 f32   (24 MB)
  unsigned short* Qb   = (unsigned short*)(ws + 38797312);    // 2x16x2048x64    (8 MB)
  unsigned short* Kb   = (unsigned short*)(ws + 47185920);    // 2x4x2048x64     (2 MB)
  unsigned short* Vb   = (unsigned short*)(ws + 49283072);    // 2x4x64x2048 ^T  (2 MB)
  unsigned short* Yb   = (unsigned short*)(ws + 51380224);    // 4096x1024 bf16  (8 MB)

  cvt_kernel<<<4096, 256, 0, stream>>>(x,  xb,             1048576);
  cvt_kernel<<<1024, 256, 0, stream>>>(Wq, Wcat,            262144);
  cvt_kernel<<<256,  256, 0, stream>>>(Wk, Wcat + 1048576,   65536);
  cvt_kernel<<<256,  256, 0, stream>>>(Wv, Wcat + 1310720,   65536);
  cvt_kernel<<<1024, 256, 0, stream>>>(Wo, Wob,             262144);

  gemm_bt<<<dim3(12, 32), 256, 0, stream>>>(xb, Wcat, qkv, 4096, 1536, 1024);
  rope_pack<<<24576, 256, 0, stream>>>(qkv, rc, rs, Qb, Kb, Vb);
  attn_kernel<<<dim3(16, 32), 256, 0, stream>>>(Qb, Kb, Vb, Yb);
  gemm_bt<<<dim3(8, 32), 256, 0, stream>>>(Yb, Wob, out, 4096, 1024, 1024);
}

// Round 4
// 153.401 us; speedup vs baseline: 1.5035x; 1.1505x over previous
//
#include <hip/hip_runtime.h>

// GQA attention forward: B=2,T=2048,D=1024,H=16,HKV=4,DH=64
// Pipeline: cvt(f32->bf16) -> GEMM(QKV) -> RoPE/pack -> flash attn -> GEMM(out)
// R4: attn double-buffered reg-staged K/V (1 barrier/tile, load latency hidden
//     under compute), v_cvt_pk_bf16_f32 packing, softmax scale folded into Q,
//     s_setprio around MFMA clusters.

typedef short bf16x8 __attribute__((ext_vector_type(8)));   // 8 bf16 in 4 VGPRs
typedef float f32x4 __attribute__((ext_vector_type(4)));

__device__ __forceinline__ unsigned short f2bf(float f) {
  unsigned u = __float_as_uint(f);
  u += 0x7fffu + ((u >> 16) & 1u);          // RNE (inputs finite)
  return (unsigned short)(u >> 16);
}

__device__ __forceinline__ unsigned cvt_pk_bf16(float lo, float hi) {
  unsigned r;
  asm("v_cvt_pk_bf16_f32 %0, %1, %2" : "=v"(r) : "v"(lo), "v"(hi));
  return r;
}

__device__ __forceinline__ float fexp2(float x) {
#if __has_builtin(__builtin_amdgcn_exp2f)
  return __builtin_amdgcn_exp2f(x);
#else
  return __expf(x * 0.69314718056f);
#endif
}

__device__ __forceinline__ void load_lds16(const void* g, void* l) {
  __builtin_amdgcn_global_load_lds(
      (const __attribute__((address_space(1))) void*)g,
      (__attribute__((address_space(3))) void*)l, 16, 0, 0);
}

// ---------------- f32 -> bf16 convert, 4 elems/thread ----------------
__global__ __launch_bounds__(256) void cvt_kernel(const float* __restrict__ src,
                                                  unsigned short* __restrict__ dst,
                                                  int n4) {
  int i = blockIdx.x * blockDim.x + threadIdx.x;
  if (i >= n4) return;
  float4 v = reinterpret_cast<const float4*>(src)[i];
  ushort4 o;
  o.x = f2bf(v.x); o.y = f2bf(v.y); o.z = f2bf(v.z); o.w = f2bf(v.w);
  reinterpret_cast<ushort4*>(dst)[i] = o;
}

// ---------------- bf16 GEMM, C = A * B^T (both row-major-K) ----------------
// 128x128 tile, BK=32, 4 waves (2x2), global_load_lds dwordx4 staging.
__global__ __launch_bounds__(256) void gemm_bt(const unsigned short* __restrict__ A,
                                               const unsigned short* __restrict__ B,
                                               float* __restrict__ C,
                                               int M, int N, int K) {
  __shared__ unsigned short As[128][32];   // linear (global_load_lds needs contiguity)
  __shared__ unsigned short Bs[128][32];
  const int tid  = threadIdx.x;
  const int lane = tid & 63, wave = tid >> 6;
  const int wr = wave >> 1, wc = wave & 1;
  const int m0 = blockIdx.y * 128, n0 = blockIdx.x * 128;
  const int fr = lane & 15, k8 = (lane >> 4) * 8;
  f32x4 acc[4][4] = {};
  for (int kt = 0; kt < K; kt += 32) {
    __syncthreads();
#pragma unroll
    for (int j = 0; j < 2; ++j) {
      const int cs  = (j*4 + wave);
      const int c   = cs*64 + lane;
      const int row = c >> 2, col = (c & 3) * 8;
      load_lds16(A + (size_t)(m0 + row)*K + kt + col, (char*)&As[0][0] + (size_t)cs*1024);
      load_lds16(B + (size_t)(n0 + row)*K + kt + col, (char*)&Bs[0][0] + (size_t)cs*1024);
    }
    __syncthreads();
    bf16x8 af[4], bf[4];
#pragma unroll
    for (int i = 0; i < 4; ++i) af[i] = *(const bf16x8*)&As[wr*64 + i*16 + fr][k8];
#pragma unroll
    for (int i = 0; i < 4; ++i) bf[i] = *(const bf16x8*)&Bs[wc*64 + i*16 + fr][k8];
#pragma unroll
    for (int mi = 0; mi < 4; ++mi)
#pragma unroll
      for (int ni = 0; ni < 4; ++ni)
        acc[mi][ni] = __builtin_amdgcn_mfma_f32_16x16x32_bf16(af[mi], bf[ni], acc[mi][ni], 0, 0, 0);
  }
#pragma unroll
  for (int mi = 0; mi < 4; ++mi)
#pragma unroll
    for (int ni = 0; ni < 4; ++ni)
#pragma unroll
      for (int j = 0; j < 4; ++j) {
        int row = m0 + wr*64 + mi*16 + (lane >> 4)*4 + j;
        int col = n0 + wc*64 + ni*16 + fr;
        C[(size_t)row * N + col] = acc[mi][ni][j];
      }
}

// ---------------- RoPE + repack to per-head bf16 Q/K/V ----------------
// qkv: [4096][1536] f32 (cols 0-1023 Q, 1024-1279 K, 1280-1535 V)
// Qb: [B][H][T][64] PRE-SCALED by 0.125*log2(e); Kb: [B][HKV][T][64];
// Vb TRANSPOSED: [B][HKV][64][T]
__global__ __launch_bounds__(256) void rope_pack(const float* __restrict__ qkv,
                                                 const float* __restrict__ rc,
                                                 const float* __restrict__ rs,
                                                 unsigned short* __restrict__ Qb,
                                                 unsigned short* __restrict__ Kb,
                                                 unsigned short* __restrict__ Vb) {
  const float SCLQ = 0.125f * 1.44269504089f;
  int tid = blockIdx.x * blockDim.x + threadIdx.x;   // over 4096*1536
  int col = tid % 1536;
  int m   = tid / 1536;
  int b = m >> 11, t = m & 2047;
  float v = qkv[(size_t)m * 1536 + col];
  int d = col & 63;
  if (col < 1280) {   // rope on q and k
    float cs = rc[t*64 + d], sn = rs[t*64 + d];
    float partner = qkv[(size_t)m*1536 + ((d < 32) ? col + 32 : col - 32)];
    float rot = (d < 32) ? -partner : partner;
    v = v * cs + rot * sn;
  }
  if (col < 1024) {
    int h = col >> 6;
    Qb[((size_t)((b*16 + h)*2048 + t) << 6) + d] = f2bf(v * SCLQ);
  } else if (col < 1280) {
    int kh = (col - 1024) >> 6;
    Kb[((size_t)((b*4 + kh)*2048 + t) << 6) + d] = f2bf(v);
  } else {
    int vh = (col - 1280) >> 6;
    Vb[((size_t)(b*4 + vh)*64 + d)*2048 + t] = f2bf(v);   // V^T layout [d][T]
  }
}

// ---------------- flash attention, causal, GQA, paired q-tiles ----------------
// grid (16, B*H): block p handles q-tiles qtA=31-p (always) and qtB=p (kt<=p).
// Swapped QK^T: S^T = mfma(K, Q), lane owns one q-row. Double-buffered K/V:
// global->reg issue at loop top, compute, reg->LDS write, 1 barrier/tile.
__global__ __launch_bounds__(256) void attn_kernel(const unsigned short* __restrict__ Qb,
                                                   const unsigned short* __restrict__ Kb,
                                                   const unsigned short* __restrict__ Vb,
                                                   unsigned short* __restrict__ Yb) {
  __shared__ unsigned short Ks[2][64][72];   // K tile [kv][d], double-buffered
  __shared__ unsigned short Vt[2][64][72];   // V^T tile [d][kv]
  __shared__ unsigned PpA[4][32][20];        // per-wave packed P^T [kv2][q]
  __shared__ unsigned PpB[4][32][20];
  const int p = blockIdx.x, bh = blockIdx.y;
  const int b = bh >> 4, h = bh & 15, kvh = h >> 2;
  const int qtA = 31 - p, qtB = p;
  const int nkv = qtA + 1;
  const int tid = threadIdx.x;
  const int wave = tid >> 6, lane = tid & 63;
  const int fr = lane & 15, g = lane >> 4, k8 = g * 8;
  const int srow = tid >> 3, scol = (tid & 7) * 8;   // staging coords (j adds +32 rows)
  const unsigned short* Kp = Kb + ((size_t)(b*4 + kvh)*2048) * 64;
  const unsigned short* Vp = Vb + ((size_t)(b*4 + kvh)*64) * 2048;
  const unsigned short* QpA = Qb + ((size_t)((b*16 + h)*2048 + qtA*64)) * 64;
  const unsigned short* QpB = Qb + ((size_t)((b*16 + h)*2048 + qtB*64)) * 64;
  bf16x8 qfA0 = *(const bf16x8*)(QpA + (wave*16 + fr)*64 + k8);
  bf16x8 qfA1 = *(const bf16x8*)(QpA + (wave*16 + fr)*64 + 32 + k8);
  bf16x8 qfB0 = *(const bf16x8*)(QpB + (wave*16 + fr)*64 + k8);
  bf16x8 qfB1 = *(const bf16x8*)(QpB + (wave*16 + fr)*64 + 32 + k8);
  float mA = -3.0e38f, lA = 0.f, mB = -3.0e38f, lB = 0.f;
  f32x4 accA[4] = {}, accB[4] = {};          // O^T: d=dt*16+g*4+j, q=fr
  const int qgA = qtA*64 + wave*16 + fr;
  const int qgB = qtB*64 + wave*16 + fr;

  bf16x8 kreg[2], vreg[2];
  // prologue: stage tile 0
#pragma unroll
  for (int j = 0; j < 2; ++j) {
    kreg[j] = *(const bf16x8*)(Kp + (size_t)(srow + j*32)*64 + scol);
    vreg[j] = *(const bf16x8*)(Vp + (size_t)(srow + j*32)*2048 + scol);
  }
#pragma unroll
  for (int j = 0; j < 2; ++j) {
    *(bf16x8*)&Ks[0][srow + j*32][scol] = kreg[j];
    *(bf16x8*)&Vt[0][srow + j*32][scol] = vreg[j];
  }
  __syncthreads();

  for (int kt = 0; kt < nkv; ++kt) {
    const int kv0 = kt * 64;
    const int cur = kt & 1;
    const bool actB = (kt <= qtB);
    const bool more = (kt + 1 < nkv);
    // issue next tile's global loads (latency hides under compute below)
    if (more) {
      const size_t nv0 = (size_t)(kt + 1) * 64;
#pragma unroll
      for (int j = 0; j < 2; ++j) {
        kreg[j] = *(const bf16x8*)(Kp + (nv0 + srow + j*32)*64 + scol);
        vreg[j] = *(const bf16x8*)(Vp + (size_t)(srow + j*32)*2048 + nv0 + scol);
      }
    }
    // QK^T swapped: sX[n] = S^T[kv=n*16+g*4+r][q=fr]
    f32x4 sA[4] = {}, sB[4] = {};
    __builtin_amdgcn_s_setprio(1);
#pragma unroll
    for (int n = 0; n < 4; ++n) {
      bf16x8 kf0 = *(const bf16x8*)&Ks[cur][n*16 + fr][k8];
      sA[n] = __builtin_amdgcn_mfma_f32_16x16x32_bf16(kf0, qfA0, sA[n], 0, 0, 0);
      if (actB) sB[n] = __builtin_amdgcn_mfma_f32_16x16x32_bf16(kf0, qfB0, sB[n], 0, 0, 0);
      bf16x8 kf1 = *(const bf16x8*)&Ks[cur][n*16 + fr][32 + k8];
      sA[n] = __builtin_amdgcn_mfma_f32_16x16x32_bf16(kf1, qfA1, sA[n], 0, 0, 0);
      if (actB) sB[n] = __builtin_amdgcn_mfma_f32_16x16x32_bf16(kf1, qfB1, sB[n], 0, 0, 0);
    }
    __builtin_amdgcn_s_setprio(0);
    // ---- softmax A (lane-local row; values already in exp2 domain) ----
    {
      const bool diag = (kt == qtA);
      float sv[4][4];
#pragma unroll
      for (int n = 0; n < 4; ++n)
#pragma unroll
        for (int r = 0; r < 4; ++r) {
          float x = sA[n][r];
          if (diag && (kv0 + n*16 + g*4 + r > qgA)) x = -3.0e38f;
          sv[n][r] = x;
        }
      float t4[4];
#pragma unroll
      for (int n = 0; n < 4; ++n)
        t4[n] = fmaxf(fmaxf(sv[n][0], sv[n][1]), fmaxf(sv[n][2], sv[n][3]));
      float tm = fmaxf(fmaxf(t4[0], t4[1]), fmaxf(t4[2], t4[3]));
      tm = fmaxf(tm, __shfl_xor(tm, 16));
      tm = fmaxf(tm, __shfl_xor(tm, 32));
      float mn = fmaxf(mA, tm);
      float alpha = fexp2(mA - mn);
      mA = mn;
      float rsum = 0.f;
#pragma unroll
      for (int n = 0; n < 4; ++n)
#pragma unroll
        for (int r2 = 0; r2 < 2; ++r2) {
          float p0 = fexp2(sv[n][2*r2]   - mn);
          float p1 = fexp2(sv[n][2*r2+1] - mn);
          rsum += p0 + p1;
          PpA[wave][n*8 + g*2 + r2][fr] = cvt_pk_bf16(p0, p1);
        }
      rsum += __shfl_xor(rsum, 16);
      rsum += __shfl_xor(rsum, 32);
      lA = lA * alpha + rsum;
#pragma unroll
      for (int dt = 0; dt < 4; ++dt) accA[dt] *= alpha;
    }
    // ---- softmax B ----
    if (actB) {
      const bool diag = (kt == qtB);
      float sv[4][4];
#pragma unroll
      for (int n = 0; n < 4; ++n)
#pragma unroll
        for (int r = 0; r < 4; ++r) {
          float x = sB[n][r];
          if (diag && (kv0 + n*16 + g*4 + r > qgB)) x = -3.0e38f;
          sv[n][r] = x;
        }
      float t4[4];
#pragma unroll
      for (int n = 0; n < 4; ++n)
        t4[n] = fmaxf(fmaxf(sv[n][0], sv[n][1]), fmaxf(sv[n][2], sv[n][3]));
      float tm = fmaxf(fmaxf(t4[0], t4[1]), fmaxf(t4[2], t4[3]));
      tm = fmaxf(tm, __shfl_xor(tm, 16));
      tm = fmaxf(tm, __shfl_xor(tm, 32));
      float mn = fmaxf(mB, tm);
      float alpha = fexp2(mB - mn);
      mB = mn;
      float rsum = 0.f;
#pragma unroll
      for (int n = 0; n < 4; ++n)
#pragma unroll
        for (int r2 = 0; r2 < 2; ++r2) {
          float p0 = fexp2(sv[n][2*r2]   - mn);
          float p1 = fexp2(sv[n][2*r2+1] - mn);
          rsum += p0 + p1;
          PpB[wave][n*8 + g*2 + r2][fr] = cvt_pk_bf16(p0, p1);
        }
      rsum += __shfl_xor(rsum, 16);
      rsum += __shfl_xor(rsum, 32);
      lB = lB * alpha + rsum;
#pragma unroll
      for (int dt = 0; dt < 4; ++dt) accB[dt] *= alpha;
    }
    // ---- PV: O^T += V^T * P^T (same-wave LDS RAW; DS in-order per wave) ----
    __builtin_amdgcn_s_setprio(1);
#pragma unroll
    for (int c = 0; c < 2; ++c) {
      union { unsigned u[4]; bf16x8 v; } pa, pb;
#pragma unroll
      for (int i2 = 0; i2 < 4; ++i2) pa.u[i2] = PpA[wave][c*16 + g*4 + i2][fr];
      if (actB) {
#pragma unroll
        for (int i2 = 0; i2 < 4; ++i2) pb.u[i2] = PpB[wave][c*16 + g*4 + i2][fr];
      }
#pragma unroll
      for (int dt = 0; dt < 4; ++dt) {
        bf16x8 vf = *(const bf16x8*)&Vt[cur][dt*16 + fr][c*32 + k8];
        accA[dt] = __builtin_amdgcn_mfma_f32_16x16x32_bf16(vf, pa.v, accA[dt], 0, 0, 0);
        if (actB) accB[dt] = __builtin_amdgcn_mfma_f32_16x16x32_bf16(vf, pb.v, accB[dt], 0, 0, 0);
      }
    }
    __builtin_amdgcn_s_setprio(0);
    // write staged regs to the other buffer; single barrier per tile
    if (more) {
#pragma unroll
      for (int j = 0; j < 2; ++j) {
        *(bf16x8*)&Ks[cur ^ 1][srow + j*32][scol] = kreg[j];
        *(bf16x8*)&Vt[cur ^ 1][srow + j*32][scol] = vreg[j];
      }
      __syncthreads();
    }
  }
  // epilogue: lane owns q-col; y = O^T[:,q]/l -> Yb[b][t=q][h*64+d]
  {
    const float inv = 1.0f / lA;
    size_t base = ((size_t)(b*2048 + qgA) << 10) + h*64;
#pragma unroll
    for (int dt = 0; dt < 4; ++dt) {
      uint2 pk;
      pk.x = cvt_pk_bf16(accA[dt][0] * inv, accA[dt][1] * inv);
      pk.y = cvt_pk_bf16(accA[dt][2] * inv, accA[dt][3] * inv);
      *(uint2*)&Yb[base + dt*16 + g*4] = pk;
    }
  }
  {
    const float inv = 1.0f / lB;
    size_t base = ((size_t)(b*2048 + qgB) << 10) + h*64;
#pragma unroll
    for (int dt = 0; dt < 4; ++dt) {
      uint2 pk;
      pk.x = cvt_pk_bf16(accB[dt][0] * inv, accB[dt][1] * inv);
      pk.y = cvt_pk_bf16(accB[dt][2] * inv, accB[dt][3] * inv);
      *(uint2*)&Yb[base + dt*16 + g*4] = pk;
    }
  }
}

extern "C" void kernel_launch(void* const* d_in, const int* in_sizes, int n_in,
                              void* d_out, int out_size, void* d_ws, size_t ws_size,
                              hipStream_t stream) {
  const float* x  = (const float*)d_in[0];
  const float* rc = (const float*)d_in[1];
  const float* rs = (const float*)d_in[2];
  // d_in[3] = attn_mask: pure causal -1e9, implemented analytically
  const float* Wq = (const float*)d_in[4];
  const float* Wk = (const float*)d_in[5];
  const float* Wv = (const float*)d_in[6];
  const float* Wo = (const float*)d_in[7];
  float* out = (float*)d_out;

  char* ws = (char*)d_ws;
  unsigned short* xb   = (unsigned short*)(ws);               // 4096x1024 bf16  (8 MB)
  unsigned short* Wcat = (unsigned short*)(ws + 8388608);     // 1536x1024 bf16  (3 MB)
  unsigned short* Wob  = (unsigned short*)(ws + 11534336);    // 1024x1024 bf16  (2 MB)
  float*          qkv  = (float*)(ws + 13631488);             // 4096x1536 f32   (24 MB)
  unsigned short* Qb   = (unsigned short*)(ws + 38797312);    // 2x16x2048x64    (8 MB)
  unsigned short* Kb   = (unsigned short*)(ws + 47185920);    // 2x4x2048x64     (2 MB)
  unsigned short* Vb   = (unsigned short*)(ws + 49283072);    // 2x4x64x2048 ^T  (2 MB)
  unsigned short* Yb   = (unsigned short*)(ws + 51380224);    // 4096x1024 bf16  (8 MB)

  cvt_kernel<<<4096, 256, 0, stream>>>(x,  xb,             1048576);
  cvt_kernel<<<1024, 256, 0, stream>>>(Wq, Wcat,            262144);
  cvt_kernel<<<256,  256, 0, stream>>>(Wk, Wcat + 1048576,   65536);
  cvt_kernel<<<256,  256, 0, stream>>>(Wv, Wcat + 1310720,   65536);
  cvt_kernel<<<1024, 256, 0, stream>>>(Wo, Wob,             262144);

  gemm_bt<<<dim3(12, 32), 256, 0, stream>>>(xb, Wcat, qkv, 4096, 1536, 1024);
  rope_pack<<<24576, 256, 0, stream>>>(qkv, rc, rs, Qb, Kb, Vb);
  attn_kernel<<<dim3(16, 32), 256, 0, stream>>>(Qb, Kb, Vb, Yb);
  gemm_bt<<<dim3(8, 32), 256, 0, stream>>>(Yb, Wob, out, 4096, 1024, 1024);
}

// Round 6
// 135.001 us; speedup vs baseline: 1.7084x; 1.1363x over previous
//
#include <hip/hip_runtime.h>

// GQA attention forward: B=2,T=2048,D=1024,H=16,HKV=4,DH=64
// Pipeline: cvt(x) + cvt(W) -> GEMM(QKV)+RoPE-fused -> flash attn -> GEMM(out)
// R6 (bisect of R5 NaN): revert defer-max TRIGGER to R4's always-rescale;
//     keep per-lane deferred denominator (exact telescoped equivalent) and
//     keep GEMM-RoPE fusion + merged weight cvt.

typedef short bf16x8 __attribute__((ext_vector_type(8)));   // 8 bf16 in 4 VGPRs
typedef float f32x4 __attribute__((ext_vector_type(4)));

__device__ __forceinline__ unsigned short f2bf(float f) {
  unsigned u = __float_as_uint(f);
  u += 0x7fffu + ((u >> 16) & 1u);          // RNE (inputs finite)
  return (unsigned short)(u >> 16);
}

__device__ __forceinline__ unsigned cvt_pk_bf16(float lo, float hi) {
  unsigned r;
  asm("v_cvt_pk_bf16_f32 %0, %1, %2" : "=v"(r) : "v"(lo), "v"(hi));
  return r;
}

__device__ __forceinline__ float fexp2(float x) {
#if __has_builtin(__builtin_amdgcn_exp2f)
  return __builtin_amdgcn_exp2f(x);
#else
  return __expf(x * 0.69314718056f);
#endif
}

__device__ __forceinline__ void load_lds16(const void* g, void* l) {
  __builtin_amdgcn_global_load_lds(
      (const __attribute__((address_space(1))) void*)g,
      (__attribute__((address_space(3))) void*)l, 16, 0, 0);
}

// ---------------- f32 -> bf16 convert, 4 elems/thread ----------------
__global__ __launch_bounds__(256) void cvt_kernel(const float* __restrict__ src,
                                                  unsigned short* __restrict__ dst,
                                                  int n4) {
  int i = blockIdx.x * blockDim.x + threadIdx.x;
  if (i >= n4) return;
  float4 v = reinterpret_cast<const float4*>(src)[i];
  ushort4 o;
  o.x = f2bf(v.x); o.y = f2bf(v.y); o.z = f2bf(v.z); o.w = f2bf(v.w);
  reinterpret_cast<ushort4*>(dst)[i] = o;
}

// ---------------- all-weight f32 -> bf16 convert (one launch) ----------------
__global__ __launch_bounds__(256) void cvt_w4(const float* __restrict__ Wq,
                                              const float* __restrict__ Wk,
                                              const float* __restrict__ Wv,
                                              const float* __restrict__ Wo,
                                              unsigned short* __restrict__ Wcat,
                                              unsigned short* __restrict__ Wob) {
  int i = blockIdx.x * blockDim.x + threadIdx.x;   // 0..655359
  const float* src; unsigned short* dst; int off;
  if (i < 262144)      { src = Wq; dst = Wcat;           off = i; }
  else if (i < 327680) { src = Wk; dst = Wcat + 1048576; off = i - 262144; }
  else if (i < 393216) { src = Wv; dst = Wcat + 1310720; off = i - 327680; }
  else                 { src = Wo; dst = Wob;            off = i - 393216; }
  float4 v = reinterpret_cast<const float4*>(src)[off];
  ushort4 o;
  o.x = f2bf(v.x); o.y = f2bf(v.y); o.z = f2bf(v.z); o.w = f2bf(v.w);
  reinterpret_cast<ushort4*>(dst)[off] = o;
}

// ---------------- bf16 GEMM, C = A * B^T (both row-major-K) ----------------
__global__ __launch_bounds__(256) void gemm_bt(const unsigned short* __restrict__ A,
                                               const unsigned short* __restrict__ B,
                                               float* __restrict__ C,
                                               int M, int N, int K) {
  __shared__ unsigned short As[128][32];
  __shared__ unsigned short Bs[128][32];
  const int tid  = threadIdx.x;
  const int lane = tid & 63, wave = tid >> 6;
  const int wr = wave >> 1, wc = wave & 1;
  const int m0 = blockIdx.y * 128, n0 = blockIdx.x * 128;
  const int fr = lane & 15, k8 = (lane >> 4) * 8;
  f32x4 acc[4][4] = {};
  for (int kt = 0; kt < K; kt += 32) {
    __syncthreads();
#pragma unroll
    for (int j = 0; j < 2; ++j) {
      const int cs  = (j*4 + wave);
      const int c   = cs*64 + lane;
      const int row = c >> 2, col = (c & 3) * 8;
      load_lds16(A + (size_t)(m0 + row)*K + kt + col, (char*)&As[0][0] + (size_t)cs*1024);
      load_lds16(B + (size_t)(n0 + row)*K + kt + col, (char*)&Bs[0][0] + (size_t)cs*1024);
    }
    __syncthreads();
    bf16x8 af[4], bf[4];
#pragma unroll
    for (int i = 0; i < 4; ++i) af[i] = *(const bf16x8*)&As[wr*64 + i*16 + fr][k8];
#pragma unroll
    for (int i = 0; i < 4; ++i) bf[i] = *(const bf16x8*)&Bs[wc*64 + i*16 + fr][k8];
#pragma unroll
    for (int mi = 0; mi < 4; ++mi)
#pragma unroll
      for (int ni = 0; ni < 4; ++ni)
        acc[mi][ni] = __builtin_amdgcn_mfma_f32_16x16x32_bf16(af[mi], bf[ni], acc[mi][ni], 0, 0, 0);
  }
#pragma unroll
  for (int mi = 0; mi < 4; ++mi)
#pragma unroll
    for (int ni = 0; ni < 4; ++ni)
#pragma unroll
      for (int j = 0; j < 4; ++j) {
        int row = m0 + wr*64 + mi*16 + (lane >> 4)*4 + j;
        int col = n0 + wc*64 + ni*16 + fr;
        C[(size_t)row * N + col] = acc[mi][ni][j];
      }
}

// ---------------- QKV GEMM with fused RoPE + pack epilogue ----------------
// C = xb(4096x1024) * Wcat^T(1536x1024). Each wave-col is one 64-wide head
// chunk; rope partner d^32 is acc[mi][ni^2][j] (same thread).
__global__ __launch_bounds__(256) void gemm_qkv_rope(const unsigned short* __restrict__ A,
                                                     const unsigned short* __restrict__ Bw,
                                                     const float* __restrict__ rc,
                                                     const float* __restrict__ rs,
                                                     unsigned short* __restrict__ Qb,
                                                     unsigned short* __restrict__ Kb,
                                                     unsigned short* __restrict__ Vb) {
  const int K = 1024;
  __shared__ unsigned short As[128][32];
  __shared__ unsigned short Bs[128][32];
  const int tid  = threadIdx.x;
  const int lane = tid & 63, wave = tid >> 6;
  const int wr = wave >> 1, wc = wave & 1;
  const int m0 = blockIdx.y * 128, n0 = blockIdx.x * 128;
  const int fr = lane & 15, k8 = (lane >> 4) * 8;
  f32x4 acc[4][4] = {};
  for (int kt = 0; kt < K; kt += 32) {
    __syncthreads();
#pragma unroll
    for (int j = 0; j < 2; ++j) {
      const int cs  = (j*4 + wave);
      const int c   = cs*64 + lane;
      const int row = c >> 2, col = (c & 3) * 8;
      load_lds16(A  + (size_t)(m0 + row)*K + kt + col, (char*)&As[0][0] + (size_t)cs*1024);
      load_lds16(Bw + (size_t)(n0 + row)*K + kt + col, (char*)&Bs[0][0] + (size_t)cs*1024);
    }
    __syncthreads();
    bf16x8 af[4], bf[4];
#pragma unroll
    for (int i = 0; i < 4; ++i) af[i] = *(const bf16x8*)&As[wr*64 + i*16 + fr][k8];
#pragma unroll
    for (int i = 0; i < 4; ++i) bf[i] = *(const bf16x8*)&Bs[wc*64 + i*16 + fr][k8];
#pragma unroll
    for (int mi = 0; mi < 4; ++mi)
#pragma unroll
      for (int ni = 0; ni < 4; ++ni)
        acc[mi][ni] = __builtin_amdgcn_mfma_f32_16x16x32_bf16(af[mi], bf[ni], acc[mi][ni], 0, 0, 0);
  }
  // fused epilogue
  const int rg = lane >> 4;
  const float SCLQ = 0.125f * 1.44269504089f;
  const int colbase = n0 + wc*64;            // 64-aligned head chunk (uniform/wave)
#pragma unroll
  for (int mi = 0; mi < 4; ++mi) {
#pragma unroll
    for (int j = 0; j < 4; ++j) {
      const int m = m0 + wr*64 + mi*16 + rg*4 + j;
      const int b = m >> 11, t = m & 2047;
      if (colbase < 1280) {                  // Q or K: apply rope
        float vr[4];
#pragma unroll
        for (int ni = 0; ni < 4; ++ni) {
          const int d = ni*16 + fr;
          float cs = rc[t*64 + d], sn = rs[t*64 + d];
          float x = acc[mi][ni][j];
          float partner = acc[mi][ni ^ 2][j];
          float rot = (ni < 2) ? -partner : partner;
          vr[ni] = x * cs + rot * sn;
        }
        if (colbase < 1024) {
          const int h = colbase >> 6;
          size_t base = ((size_t)((b*16 + h)*2048 + t) << 6);
#pragma unroll
          for (int ni = 0; ni < 4; ++ni) Qb[base + ni*16 + fr] = f2bf(vr[ni] * SCLQ);
        } else {
          const int kh = (colbase - 1024) >> 6;
          size_t base = ((size_t)((b*4 + kh)*2048 + t) << 6);
#pragma unroll
          for (int ni = 0; ni < 4; ++ni) Kb[base + ni*16 + fr] = f2bf(vr[ni]);
        }
      } else {                               // V: no rope, transposed store
        const int vh = (colbase - 1280) >> 6;
#pragma unroll
        for (int ni = 0; ni < 4; ++ni) {
          const int d = ni*16 + fr;
          Vb[((size_t)((b*4 + vh)*64 + d))*2048 + t] = f2bf(acc[mi][ni][j]);
        }
      }
    }
  }
}

// ---------------- flash attention, causal, GQA, paired q-tiles ----------------
// grid (16, B*H): block p handles q-tiles qtA=31-p (always) and qtB=p (kt<=p).
// Swapped QK^T (lane owns one q-row). Double-buffered reg-staged K/V.
// R6: R4's per-tile rescale (proven), per-lane denominator (epilogue reduce).
__global__ __launch_bounds__(256) void attn_kernel(const unsigned short* __restrict__ Qb,
                                                   const unsigned short* __restrict__ Kb,
                                                   const unsigned short* __restrict__ Vb,
                                                   unsigned short* __restrict__ Yb) {
  __shared__ unsigned short Ks[2][64][72];   // K tile [kv][d], double-buffered
  __shared__ unsigned short Vt[2][64][72];   // V^T tile [d][kv]
  __shared__ unsigned PpA[4][32][20];        // per-wave packed P^T [kv2][q]
  __shared__ unsigned PpB[4][32][20];
  const int p = blockIdx.x, bh = blockIdx.y;
  const int b = bh >> 4, h = bh & 15, kvh = h >> 2;
  const int qtA = 31 - p, qtB = p;
  const int nkv = qtA + 1;
  const int tid = threadIdx.x;
  const int wave = tid >> 6, lane = tid & 63;
  const int fr = lane & 15, g = lane >> 4, k8 = g * 8;
  const int srow = tid >> 3, scol = (tid & 7) * 8;
  const unsigned short* Kp = Kb + ((size_t)(b*4 + kvh)*2048) * 64;
  const unsigned short* Vp = Vb + ((size_t)(b*4 + kvh)*64) * 2048;
  const unsigned short* QpA = Qb + ((size_t)((b*16 + h)*2048 + qtA*64)) * 64;
  const unsigned short* QpB = Qb + ((size_t)((b*16 + h)*2048 + qtB*64)) * 64;
  bf16x8 qfA0 = *(const bf16x8*)(QpA + (wave*16 + fr)*64 + k8);
  bf16x8 qfA1 = *(const bf16x8*)(QpA + (wave*16 + fr)*64 + 32 + k8);
  bf16x8 qfB0 = *(const bf16x8*)(QpB + (wave*16 + fr)*64 + k8);
  bf16x8 qfB1 = *(const bf16x8*)(QpB + (wave*16 + fr)*64 + 32 + k8);
  float mA = -3.0e38f, lsA = 0.f, mB = -3.0e38f, lsB = 0.f;  // ls per-lane
  f32x4 accA[4] = {}, accB[4] = {};          // O^T: d=dt*16+g*4+j, q=fr
  const int qgA = qtA*64 + wave*16 + fr;
  const int qgB = qtB*64 + wave*16 + fr;

  bf16x8 kreg[2], vreg[2];
#pragma unroll
  for (int j = 0; j < 2; ++j) {
    kreg[j] = *(const bf16x8*)(Kp + (size_t)(srow + j*32)*64 + scol);
    vreg[j] = *(const bf16x8*)(Vp + (size_t)(srow + j*32)*2048 + scol);
  }
#pragma unroll
  for (int j = 0; j < 2; ++j) {
    *(bf16x8*)&Ks[0][srow + j*32][scol] = kreg[j];
    *(bf16x8*)&Vt[0][srow + j*32][scol] = vreg[j];
  }
  __syncthreads();

  for (int kt = 0; kt < nkv; ++kt) {
    const int kv0 = kt * 64;
    const int cur = kt & 1;
    const bool actB = (kt <= qtB);
    const bool more = (kt + 1 < nkv);
    if (more) {
      const size_t nv0 = (size_t)(kt + 1) * 64;
#pragma unroll
      for (int j = 0; j < 2; ++j) {
        kreg[j] = *(const bf16x8*)(Kp + (nv0 + srow + j*32)*64 + scol);
        vreg[j] = *(const bf16x8*)(Vp + (size_t)(srow + j*32)*2048 + nv0 + scol);
      }
    }
    // QK^T swapped: sX[n] = S^T[kv=n*16+g*4+r][q=fr]
    f32x4 sA[4] = {}, sB[4] = {};
    __builtin_amdgcn_s_setprio(1);
#pragma unroll
    for (int n = 0; n < 4; ++n) {
      bf16x8 kf0 = *(const bf16x8*)&Ks[cur][n*16 + fr][k8];
      sA[n] = __builtin_amdgcn_mfma_f32_16x16x32_bf16(kf0, qfA0, sA[n], 0, 0, 0);
      if (actB) sB[n] = __builtin_amdgcn_mfma_f32_16x16x32_bf16(kf0, qfB0, sB[n], 0, 0, 0);
      bf16x8 kf1 = *(const bf16x8*)&Ks[cur][n*16 + fr][32 + k8];
      sA[n] = __builtin_amdgcn_mfma_f32_16x16x32_bf16(kf1, qfA1, sA[n], 0, 0, 0);
      if (actB) sB[n] = __builtin_amdgcn_mfma_f32_16x16x32_bf16(kf1, qfB1, sB[n], 0, 0, 0);
    }
    __builtin_amdgcn_s_setprio(0);
    // ---- softmax A (always-rescale; per-lane partial denominator) ----
    {
      float sv[4][4];
      if (kt == qtA) {           // diagonal tile: apply causal mask
#pragma unroll
        for (int n = 0; n < 4; ++n)
#pragma unroll
          for (int r = 0; r < 4; ++r)
            sv[n][r] = (kv0 + n*16 + g*4 + r > qgA) ? -3.0e38f : sA[n][r];
      } else {
#pragma unroll
        for (int n = 0; n < 4; ++n)
#pragma unroll
          for (int r = 0; r < 4; ++r) sv[n][r] = sA[n][r];
      }
      float t4[4];
#pragma unroll
      for (int n = 0; n < 4; ++n)
        t4[n] = fmaxf(fmaxf(sv[n][0], sv[n][1]), fmaxf(sv[n][2], sv[n][3]));
      float tm = fmaxf(fmaxf(t4[0], t4[1]), fmaxf(t4[2], t4[3]));
      tm = fmaxf(tm, __shfl_xor(tm, 16));
      tm = fmaxf(tm, __shfl_xor(tm, 32));
      float mn = fmaxf(mA, tm);
      float al = fexp2(mA - mn);
      mA = mn;
      lsA *= al;
#pragma unroll
      for (int dt = 0; dt < 4; ++dt) accA[dt] *= al;
#pragma unroll
      for (int n = 0; n < 4; ++n)
#pragma unroll
        for (int r2 = 0; r2 < 2; ++r2) {
          float p0 = fexp2(sv[n][2*r2]   - mA);
          float p1 = fexp2(sv[n][2*r2+1] - mA);
          lsA += p0 + p1;
          PpA[wave][n*8 + g*2 + r2][fr] = cvt_pk_bf16(p0, p1);
        }
    }
    // ---- softmax B ----
    if (actB) {
      float sv[4][4];
      if (kt == qtB) {
#pragma unroll
        for (int n = 0; n < 4; ++n)
#pragma unroll
          for (int r = 0; r < 4; ++r)
            sv[n][r] = (kv0 + n*16 + g*4 + r > qgB) ? -3.0e38f : sB[n][r];
      } else {
#pragma unroll
        for (int n = 0; n < 4; ++n)
#pragma unroll
          for (int r = 0; r < 4; ++r) sv[n][r] = sB[n][r];
      }
      float t4[4];
#pragma unroll
      for (int n = 0; n < 4; ++n)
        t4[n] = fmaxf(fmaxf(sv[n][0], sv[n][1]), fmaxf(sv[n][2], sv[n][3]));
      float tm = fmaxf(fmaxf(t4[0], t4[1]), fmaxf(t4[2], t4[3]));
      tm = fmaxf(tm, __shfl_xor(tm, 16));
      tm = fmaxf(tm, __shfl_xor(tm, 32));
      float mn = fmaxf(mB, tm);
      float al = fexp2(mB - mn);
      mB = mn;
      lsB *= al;
#pragma unroll
      for (int dt = 0; dt < 4; ++dt) accB[dt] *= al;
#pragma unroll
      for (int n = 0; n < 4; ++n)
#pragma unroll
        for (int r2 = 0; r2 < 2; ++r2) {
          float p0 = fexp2(sv[n][2*r2]   - mB);
          float p1 = fexp2(sv[n][2*r2+1] - mB);
          lsB += p0 + p1;
          PpB[wave][n*8 + g*2 + r2][fr] = cvt_pk_bf16(p0, p1);
        }
    }
    // ---- PV: O^T += V^T * P^T (same-wave LDS RAW; DS in-order per wave) ----
    __builtin_amdgcn_s_setprio(1);
#pragma unroll
    for (int c = 0; c < 2; ++c) {
      union { unsigned u[4]; bf16x8 v; } pa, pb;
#pragma unroll
      for (int i2 = 0; i2 < 4; ++i2) pa.u[i2] = PpA[wave][c*16 + g*4 + i2][fr];
      if (actB) {
#pragma unroll
        for (int i2 = 0; i2 < 4; ++i2) pb.u[i2] = PpB[wave][c*16 + g*4 + i2][fr];
      }
#pragma unroll
      for (int dt = 0; dt < 4; ++dt) {
        bf16x8 vf = *(const bf16x8*)&Vt[cur][dt*16 + fr][c*32 + k8];
        accA[dt] = __builtin_amdgcn_mfma_f32_16x16x32_bf16(vf, pa.v, accA[dt], 0, 0, 0);
        if (actB) accB[dt] = __builtin_amdgcn_mfma_f32_16x16x32_bf16(vf, pb.v, accB[dt], 0, 0, 0);
      }
    }
    __builtin_amdgcn_s_setprio(0);
    if (more) {
#pragma unroll
      for (int j = 0; j < 2; ++j) {
        *(bf16x8*)&Ks[cur ^ 1][srow + j*32][scol] = kreg[j];
        *(bf16x8*)&Vt[cur ^ 1][srow + j*32][scol] = vreg[j];
      }
      __syncthreads();
    }
  }
  // epilogue: reduce per-lane denominators once; lane owns q-col
  {
    float ls = lsA;
    ls += __shfl_xor(ls, 16);
    ls += __shfl_xor(ls, 32);
    const float inv = 1.0f / ls;
    size_t base = ((size_t)(b*2048 + qgA) << 10) + h*64;
#pragma unroll
    for (int dt = 0; dt < 4; ++dt) {
      uint2 pk;
      pk.x = cvt_pk_bf16(accA[dt][0] * inv, accA[dt][1] * inv);
      pk.y = cvt_pk_bf16(accA[dt][2] * inv, accA[dt][3] * inv);
      *(uint2*)&Yb[base + dt*16 + g*4] = pk;
    }
  }
  {
    float ls = lsB;
    ls += __shfl_xor(ls, 16);
    ls += __shfl_xor(ls, 32);
    const float inv = 1.0f / ls;
    size_t base = ((size_t)(b*2048 + qgB) << 10) + h*64;
#pragma unroll
    for (int dt = 0; dt < 4; ++dt) {
      uint2 pk;
      pk.x = cvt_pk_bf16(accB[dt][0] * inv, accB[dt][1] * inv);
      pk.y = cvt_pk_bf16(accB[dt][2] * inv, accB[dt][3] * inv);
      *(uint2*)&Yb[base + dt*16 + g*4] = pk;
    }
  }
}

extern "C" void kernel_launch(void* const* d_in, const int* in_sizes, int n_in,
                              void* d_out, int out_size, void* d_ws, size_t ws_size,
                              hipStream_t stream) {
  const float* x  = (const float*)d_in[0];
  const float* rc = (const float*)d_in[1];
  const float* rs = (const float*)d_in[2];
  // d_in[3] = attn_mask: pure causal -1e9, implemented analytically
  const float* Wq = (const float*)d_in[4];
  const float* Wk = (const float*)d_in[5];
  const float* Wv = (const float*)d_in[6];
  const float* Wo = (const float*)d_in[7];
  float* out = (float*)d_out;

  char* ws = (char*)d_ws;
  unsigned short* xb   = (unsigned short*)(ws);               // 4096x1024 bf16  (8 MB)
  unsigned short* Wcat = (unsigned short*)(ws + 8388608);     // 1536x1024 bf16  (3 MB)
  unsigned short* Wob  = (unsigned short*)(ws + 11534336);    // 1024x1024 bf16  (2 MB)
  unsigned short* Qb   = (unsigned short*)(ws + 38797312);    // 2x16x2048x64    (8 MB)
  unsigned short* Kb   = (unsigned short*)(ws + 47185920);    // 2x4x2048x64     (2 MB)
  unsigned short* Vb   = (unsigned short*)(ws + 49283072);    // 2x4x64x2048 ^T  (2 MB)
  unsigned short* Yb   = (unsigned short*)(ws + 51380224);    // 4096x1024 bf16  (8 MB)

  cvt_kernel<<<4096, 256, 0, stream>>>(x, xb, 1048576);
  cvt_w4<<<2560, 256, 0, stream>>>(Wq, Wk, Wv, Wo, Wcat, Wob);
  gemm_qkv_rope<<<dim3(12, 32), 256, 0, stream>>>(xb, Wcat, rc, rs, Qb, Kb, Vb);
  attn_kernel<<<dim3(16, 32), 256, 0, stream>>>(Qb, Kb, Vb, Yb);
  gemm_bt<<<dim3(8, 32), 256, 0, stream>>>(Yb, Wob, out, 4096, 1024, 1024);
}

// Round 8
// 134.833 us; speedup vs baseline: 1.7105x; 1.0012x over previous
//
#include <hip/hip_runtime.h>

// GQA attention forward: B=2,T=2048,D=1024,H=16,HKV=4,DH=64
// Pipeline: cvt(x) + cvt(W) -> GEMM(QKV)+RoPE-fused -> flash attn -> GEMM(out)
// R8: attn reverted exactly to R6 (R7's time-shared Pp races: compiler may
//     reorder per-lane non-aliasing ds ops, breaking cross-lane RAW).
//     GEMMs upgraded to 2-phase double-buffered pipeline (T3-lite):
//     stage t+1 before compute t, ONE barrier per K-step (was 2).

typedef short bf16x8 __attribute__((ext_vector_type(8)));   // 8 bf16 in 4 VGPRs
typedef float f32x4 __attribute__((ext_vector_type(4)));

__device__ __forceinline__ unsigned short f2bf(float f) {
  unsigned u = __float_as_uint(f);
  u += 0x7fffu + ((u >> 16) & 1u);          // RNE (inputs finite)
  return (unsigned short)(u >> 16);
}

__device__ __forceinline__ unsigned cvt_pk_bf16(float lo, float hi) {
  unsigned r;
  asm("v_cvt_pk_bf16_f32 %0, %1, %2" : "=v"(r) : "v"(lo), "v"(hi));
  return r;
}

__device__ __forceinline__ float fexp2(float x) {
#if __has_builtin(__builtin_amdgcn_exp2f)
  return __builtin_amdgcn_exp2f(x);
#else
  return __expf(x * 0.69314718056f);
#endif
}

__device__ __forceinline__ void load_lds16(const void* g, void* l) {
  __builtin_amdgcn_global_load_lds(
      (const __attribute__((address_space(1))) void*)g,
      (__attribute__((address_space(3))) void*)l, 16, 0, 0);
}

// ---------------- f32 -> bf16 convert, 4 elems/thread ----------------
__global__ __launch_bounds__(256) void cvt_kernel(const float* __restrict__ src,
                                                  unsigned short* __restrict__ dst,
                                                  int n4) {
  int i = blockIdx.x * blockDim.x + threadIdx.x;
  if (i >= n4) return;
  float4 v = reinterpret_cast<const float4*>(src)[i];
  ushort4 o;
  o.x = f2bf(v.x); o.y = f2bf(v.y); o.z = f2bf(v.z); o.w = f2bf(v.w);
  reinterpret_cast<ushort4*>(dst)[i] = o;
}

// ---------------- all-weight f32 -> bf16 convert (one launch) ----------------
__global__ __launch_bounds__(256) void cvt_w4(const float* __restrict__ Wq,
                                              const float* __restrict__ Wk,
                                              const float* __restrict__ Wv,
                                              const float* __restrict__ Wo,
                                              unsigned short* __restrict__ Wcat,
                                              unsigned short* __restrict__ Wob) {
  int i = blockIdx.x * blockDim.x + threadIdx.x;   // 0..655359
  const float* src; unsigned short* dst; int off;
  if (i < 262144)      { src = Wq; dst = Wcat;           off = i; }
  else if (i < 327680) { src = Wk; dst = Wcat + 1048576; off = i - 262144; }
  else if (i < 393216) { src = Wv; dst = Wcat + 1310720; off = i - 327680; }
  else                 { src = Wo; dst = Wob;            off = i - 393216; }
  float4 v = reinterpret_cast<const float4*>(src)[off];
  ushort4 o;
  o.x = f2bf(v.x); o.y = f2bf(v.y); o.z = f2bf(v.z); o.w = f2bf(v.w);
  reinterpret_cast<ushort4*>(dst)[off] = o;
}

// ---------------- bf16 GEMM, C = A * B^T, 2-phase double-buffered ----------------
// 128x128 tile, BK=32, 4 waves (2x2). Stage t+1 (global_load_lds) BEFORE
// computing t; one barrier per K-step (auto vmcnt(0) drain at barrier).
__global__ __launch_bounds__(256) void gemm_bt(const unsigned short* __restrict__ A,
                                               const unsigned short* __restrict__ B,
                                               float* __restrict__ C,
                                               int M, int N, int K) {
  __shared__ unsigned short As[2][128][32];
  __shared__ unsigned short Bs[2][128][32];
  const int tid  = threadIdx.x;
  const int lane = tid & 63, wave = tid >> 6;
  const int wr = wave >> 1, wc = wave & 1;
  const int m0 = blockIdx.y * 128, n0 = blockIdx.x * 128;
  const int fr = lane & 15, k8 = (lane >> 4) * 8;
  const int nT = K >> 5;
  f32x4 acc[4][4] = {};

  // staging geometry: 8 chunks of 1KB per array; chunk cs covers rows cs*16..+15
  const int scs0 = wave, scs1 = 4 + wave;
#define GSTAGE(sel, kt)                                                          \
  {                                                                              \
    {                                                                            \
      const int c = scs0*64 + lane, row = c >> 2, col = (c & 3) * 8;             \
      load_lds16(A + (size_t)(m0 + row)*K + (kt) + col,                          \
                 (char*)&As[sel][0][0] + (size_t)scs0*1024);                     \
      load_lds16(B + (size_t)(n0 + row)*K + (kt) + col,                          \
                 (char*)&Bs[sel][0][0] + (size_t)scs0*1024);                     \
    }                                                                            \
    {                                                                            \
      const int c = scs1*64 + lane, row = c >> 2, col = (c & 3) * 8;             \
      load_lds16(A + (size_t)(m0 + row)*K + (kt) + col,                          \
                 (char*)&As[sel][0][0] + (size_t)scs1*1024);                     \
      load_lds16(B + (size_t)(n0 + row)*K + (kt) + col,                          \
                 (char*)&Bs[sel][0][0] + (size_t)scs1*1024);                     \
    }                                                                            \
  }

  GSTAGE(0, 0);
  __syncthreads();
  for (int t = 0; t < nT; ++t) {
    const int cur = t & 1;
    if (t + 1 < nT) GSTAGE(cur ^ 1, (t + 1) * 32);
    bf16x8 af[4], bf[4];
#pragma unroll
    for (int i = 0; i < 4; ++i) af[i] = *(const bf16x8*)&As[cur][wr*64 + i*16 + fr][k8];
#pragma unroll
    for (int i = 0; i < 4; ++i) bf[i] = *(const bf16x8*)&Bs[cur][wc*64 + i*16 + fr][k8];
#pragma unroll
    for (int mi = 0; mi < 4; ++mi)
#pragma unroll
      for (int ni = 0; ni < 4; ++ni)
        acc[mi][ni] = __builtin_amdgcn_mfma_f32_16x16x32_bf16(af[mi], bf[ni], acc[mi][ni], 0, 0, 0);
    __syncthreads();   // drains vmcnt(0): next buffer ready; all reads of cur done
  }
#pragma unroll
  for (int mi = 0; mi < 4; ++mi)
#pragma unroll
    for (int ni = 0; ni < 4; ++ni)
#pragma unroll
      for (int j = 0; j < 4; ++j) {
        int row = m0 + wr*64 + mi*16 + (lane >> 4)*4 + j;
        int col = n0 + wc*64 + ni*16 + fr;
        C[(size_t)row * N + col] = acc[mi][ni][j];
      }
}

// ---------------- QKV GEMM (2-phase dbuf) with fused RoPE + pack ----------------
// C = xb(4096x1024) * Wcat^T(1536x1024). Each wave-col is one 64-wide head
// chunk; rope partner d^32 is acc[mi][ni^2][j] (same thread).
__global__ __launch_bounds__(256) void gemm_qkv_rope(const unsigned short* __restrict__ A,
                                                     const unsigned short* __restrict__ Bw,
                                                     const float* __restrict__ rc,
                                                     const float* __restrict__ rs,
                                                     unsigned short* __restrict__ Qb,
                                                     unsigned short* __restrict__ Kb,
                                                     unsigned short* __restrict__ Vb) {
  const int K = 1024;
  __shared__ unsigned short As[2][128][32];
  __shared__ unsigned short Bs[2][128][32];
  const int tid  = threadIdx.x;
  const int lane = tid & 63, wave = tid >> 6;
  const int wr = wave >> 1, wc = wave & 1;
  const int m0 = blockIdx.y * 128, n0 = blockIdx.x * 128;
  const int fr = lane & 15, k8 = (lane >> 4) * 8;
  f32x4 acc[4][4] = {};
  const int scs0 = wave, scs1 = 4 + wave;
#define QSTAGE(sel, kt)                                                          \
  {                                                                              \
    {                                                                            \
      const int c = scs0*64 + lane, row = c >> 2, col = (c & 3) * 8;             \
      load_lds16(A  + (size_t)(m0 + row)*K + (kt) + col,                         \
                 (char*)&As[sel][0][0] + (size_t)scs0*1024);                     \
      load_lds16(Bw + (size_t)(n0 + row)*K + (kt) + col,                         \
                 (char*)&Bs[sel][0][0] + (size_t)scs0*1024);                     \
    }                                                                            \
    {                                                                            \
      const int c = scs1*64 + lane, row = c >> 2, col = (c & 3) * 8;             \
      load_lds16(A  + (size_t)(m0 + row)*K + (kt) + col,                         \
                 (char*)&As[sel][0][0] + (size_t)scs1*1024);                     \
      load_lds16(Bw + (size_t)(n0 + row)*K + (kt) + col,                         \
                 (char*)&Bs[sel][0][0] + (size_t)scs1*1024);                     \
    }                                                                            \
  }
  QSTAGE(0, 0);
  __syncthreads();
  for (int t = 0; t < 32; ++t) {
    const int cur = t & 1;
    if (t + 1 < 32) QSTAGE(cur ^ 1, (t + 1) * 32);
    bf16x8 af[4], bf[4];
#pragma unroll
    for (int i = 0; i < 4; ++i) af[i] = *(const bf16x8*)&As[cur][wr*64 + i*16 + fr][k8];
#pragma unroll
    for (int i = 0; i < 4; ++i) bf[i] = *(const bf16x8*)&Bs[cur][wc*64 + i*16 + fr][k8];
#pragma unroll
    for (int mi = 0; mi < 4; ++mi)
#pragma unroll
      for (int ni = 0; ni < 4; ++ni)
        acc[mi][ni] = __builtin_amdgcn_mfma_f32_16x16x32_bf16(af[mi], bf[ni], acc[mi][ni], 0, 0, 0);
    __syncthreads();
  }
  // fused epilogue
  const int rg = lane >> 4;
  const float SCLQ = 0.125f * 1.44269504089f;
  const int colbase = n0 + wc*64;            // 64-aligned head chunk (uniform/wave)
#pragma unroll
  for (int mi = 0; mi < 4; ++mi) {
#pragma unroll
    for (int j = 0; j < 4; ++j) {
      const int m = m0 + wr*64 + mi*16 + rg*4 + j;
      const int b = m >> 11, t = m & 2047;
      if (colbase < 1280) {                  // Q or K: apply rope
        float vr[4];
#pragma unroll
        for (int ni = 0; ni < 4; ++ni) {
          const int d = ni*16 + fr;
          float cs = rc[t*64 + d], sn = rs[t*64 + d];
          float x = acc[mi][ni][j];
          float partner = acc[mi][ni ^ 2][j];
          float rot = (ni < 2) ? -partner : partner;
          vr[ni] = x * cs + rot * sn;
        }
        if (colbase < 1024) {
          const int h = colbase >> 6;
          size_t base = ((size_t)((b*16 + h)*2048 + t) << 6);
#pragma unroll
          for (int ni = 0; ni < 4; ++ni) Qb[base + ni*16 + fr] = f2bf(vr[ni] * SCLQ);
        } else {
          const int kh = (colbase - 1024) >> 6;
          size_t base = ((size_t)((b*4 + kh)*2048 + t) << 6);
#pragma unroll
          for (int ni = 0; ni < 4; ++ni) Kb[base + ni*16 + fr] = f2bf(vr[ni]);
        }
      } else {                               // V: no rope, transposed store
        const int vh = (colbase - 1280) >> 6;
#pragma unroll
        for (int ni = 0; ni < 4; ++ni) {
          const int d = ni*16 + fr;
          Vb[((size_t)((b*4 + vh)*64 + d))*2048 + t] = f2bf(acc[mi][ni][j]);
        }
      }
    }
  }
}

// ---------------- flash attention, causal, GQA, paired q-tiles ----------------
// grid (16, B*H): block p handles q-tiles qtA=31-p (always) and qtB=p (kt<=p).
// Swapped QK^T (lane owns one q-row). Double-buffered reg-staged K/V.
// R8: exact R6 kernel (two Pp buffers — R7's time-shared variant races).
__global__ __launch_bounds__(256) void attn_kernel(const unsigned short* __restrict__ Qb,
                                                   const unsigned short* __restrict__ Kb,
                                                   const unsigned short* __restrict__ Vb,
                                                   unsigned short* __restrict__ Yb) {
  __shared__ unsigned short Ks[2][64][72];   // K tile [kv][d], double-buffered
  __shared__ unsigned short Vt[2][64][72];   // V^T tile [d][kv]
  __shared__ unsigned PpA[4][32][20];        // per-wave packed P^T [kv2][q]
  __shared__ unsigned PpB[4][32][20];
  const int p = blockIdx.x, bh = blockIdx.y;
  const int b = bh >> 4, h = bh & 15, kvh = h >> 2;
  const int qtA = 31 - p, qtB = p;
  const int nkv = qtA + 1;
  const int tid = threadIdx.x;
  const int wave = tid >> 6, lane = tid & 63;
  const int fr = lane & 15, g = lane >> 4, k8 = g * 8;
  const int srow = tid >> 3, scol = (tid & 7) * 8;
  const unsigned short* Kp = Kb + ((size_t)(b*4 + kvh)*2048) * 64;
  const unsigned short* Vp = Vb + ((size_t)(b*4 + kvh)*64) * 2048;
  const unsigned short* QpA = Qb + ((size_t)((b*16 + h)*2048 + qtA*64)) * 64;
  const unsigned short* QpB = Qb + ((size_t)((b*16 + h)*2048 + qtB*64)) * 64;
  bf16x8 qfA0 = *(const bf16x8*)(QpA + (wave*16 + fr)*64 + k8);
  bf16x8 qfA1 = *(const bf16x8*)(QpA + (wave*16 + fr)*64 + 32 + k8);
  bf16x8 qfB0 = *(const bf16x8*)(QpB + (wave*16 + fr)*64 + k8);
  bf16x8 qfB1 = *(const bf16x8*)(QpB + (wave*16 + fr)*64 + 32 + k8);
  float mA = -3.0e38f, lsA = 0.f, mB = -3.0e38f, lsB = 0.f;  // ls per-lane
  f32x4 accA[4] = {}, accB[4] = {};          // O^T: d=dt*16+g*4+j, q=fr
  const int qgA = qtA*64 + wave*16 + fr;
  const int qgB = qtB*64 + wave*16 + fr;

  bf16x8 kreg[2], vreg[2];
#pragma unroll
  for (int j = 0; j < 2; ++j) {
    kreg[j] = *(const bf16x8*)(Kp + (size_t)(srow + j*32)*64 + scol);
    vreg[j] = *(const bf16x8*)(Vp + (size_t)(srow + j*32)*2048 + scol);
  }
#pragma unroll
  for (int j = 0; j < 2; ++j) {
    *(bf16x8*)&Ks[0][srow + j*32][scol] = kreg[j];
    *(bf16x8*)&Vt[0][srow + j*32][scol] = vreg[j];
  }
  __syncthreads();

  for (int kt = 0; kt < nkv; ++kt) {
    const int kv0 = kt * 64;
    const int cur = kt & 1;
    const bool actB = (kt <= qtB);
    const bool more = (kt + 1 < nkv);
    if (more) {
      const size_t nv0 = (size_t)(kt + 1) * 64;
#pragma unroll
      for (int j = 0; j < 2; ++j) {
        kreg[j] = *(const bf16x8*)(Kp + (nv0 + srow + j*32)*64 + scol);
        vreg[j] = *(const bf16x8*)(Vp + (size_t)(srow + j*32)*2048 + nv0 + scol);
      }
    }
    // QK^T swapped: sX[n] = S^T[kv=n*16+g*4+r][q=fr]
    f32x4 sA[4] = {}, sB[4] = {};
    __builtin_amdgcn_s_setprio(1);
#pragma unroll
    for (int n = 0; n < 4; ++n) {
      bf16x8 kf0 = *(const bf16x8*)&Ks[cur][n*16 + fr][k8];
      sA[n] = __builtin_amdgcn_mfma_f32_16x16x32_bf16(kf0, qfA0, sA[n], 0, 0, 0);
      if (actB) sB[n] = __builtin_amdgcn_mfma_f32_16x16x32_bf16(kf0, qfB0, sB[n], 0, 0, 0);
      bf16x8 kf1 = *(const bf16x8*)&Ks[cur][n*16 + fr][32 + k8];
      sA[n] = __builtin_amdgcn_mfma_f32_16x16x32_bf16(kf1, qfA1, sA[n], 0, 0, 0);
      if (actB) sB[n] = __builtin_amdgcn_mfma_f32_16x16x32_bf16(kf1, qfB1, sB[n], 0, 0, 0);
    }
    __builtin_amdgcn_s_setprio(0);
    // ---- softmax A (always-rescale; per-lane partial denominator) ----
    {
      float sv[4][4];
      if (kt == qtA) {           // diagonal tile: apply causal mask
#pragma unroll
        for (int n = 0; n < 4; ++n)
#pragma unroll
          for (int r = 0; r < 4; ++r)
            sv[n][r] = (kv0 + n*16 + g*4 + r > qgA) ? -3.0e38f : sA[n][r];
      } else {
#pragma unroll
        for (int n = 0; n < 4; ++n)
#pragma unroll
          for (int r = 0; r < 4; ++r) sv[n][r] = sA[n][r];
      }
      float t4[4];
#pragma unroll
      for (int n = 0; n < 4; ++n)
        t4[n] = fmaxf(fmaxf(sv[n][0], sv[n][1]), fmaxf(sv[n][2], sv[n][3]));
      float tm = fmaxf(fmaxf(t4[0], t4[1]), fmaxf(t4[2], t4[3]));
      tm = fmaxf(tm, __shfl_xor(tm, 16));
      tm = fmaxf(tm, __shfl_xor(tm, 32));
      float mn = fmaxf(mA, tm);
      float al = fexp2(mA - mn);
      mA = mn;
      lsA *= al;
#pragma unroll
      for (int dt = 0; dt < 4; ++dt) accA[dt] *= al;
#pragma unroll
      for (int n = 0; n < 4; ++n)
#pragma unroll
        for (int r2 = 0; r2 < 2; ++r2) {
          float p0 = fexp2(sv[n][2*r2]   - mA);
          float p1 = fexp2(sv[n][2*r2+1] - mA);
          lsA += p0 + p1;
          PpA[wave][n*8 + g*2 + r2][fr] = cvt_pk_bf16(p0, p1);
        }
    }
    // ---- softmax B ----
    if (actB) {
      float sv[4][4];
      if (kt == qtB) {
#pragma unroll
        for (int n = 0; n < 4; ++n)
#pragma unroll
          for (int r = 0; r < 4; ++r)
            sv[n][r] = (kv0 + n*16 + g*4 + r > qgB) ? -3.0e38f : sB[n][r];
      } else {
#pragma unroll
        for (int n = 0; n < 4; ++n)
#pragma unroll
          for (int r = 0; r < 4; ++r) sv[n][r] = sB[n][r];
      }
      float t4[4];
#pragma unroll
      for (int n = 0; n < 4; ++n)
        t4[n] = fmaxf(fmaxf(sv[n][0], sv[n][1]), fmaxf(sv[n][2], sv[n][3]));
      float tm = fmaxf(fmaxf(t4[0], t4[1]), fmaxf(t4[2], t4[3]));
      tm = fmaxf(tm, __shfl_xor(tm, 16));
      tm = fmaxf(tm, __shfl_xor(tm, 32));
      float mn = fmaxf(mB, tm);
      float al = fexp2(mB - mn);
      mB = mn;
      lsB *= al;
#pragma unroll
      for (int dt = 0; dt < 4; ++dt) accB[dt] *= al;
#pragma unroll
      for (int n = 0; n < 4; ++n)
#pragma unroll
        for (int r2 = 0; r2 < 2; ++r2) {
          float p0 = fexp2(sv[n][2*r2]   - mB);
          float p1 = fexp2(sv[n][2*r2+1] - mB);
          lsB += p0 + p1;
          PpB[wave][n*8 + g*2 + r2][fr] = cvt_pk_bf16(p0, p1);
        }
    }
    // ---- PV: O^T += V^T * P^T (same-wave LDS RAW; DS in-order per wave) ----
    __builtin_amdgcn_s_setprio(1);
#pragma unroll
    for (int c = 0; c < 2; ++c) {
      union { unsigned u[4]; bf16x8 v; } pa, pb;
#pragma unroll
      for (int i2 = 0; i2 < 4; ++i2) pa.u[i2] = PpA[wave][c*16 + g*4 + i2][fr];
      if (actB) {
#pragma unroll
        for (int i2 = 0; i2 < 4; ++i2) pb.u[i2] = PpB[wave][c*16 + g*4 + i2][fr];
      }
#pragma unroll
      for (int dt = 0; dt < 4; ++dt) {
        bf16x8 vf = *(const bf16x8*)&Vt[cur][dt*16 + fr][c*32 + k8];
        accA[dt] = __builtin_amdgcn_mfma_f32_16x16x32_bf16(vf, pa.v, accA[dt], 0, 0, 0);
        if (actB) accB[dt] = __builtin_amdgcn_mfma_f32_16x16x32_bf16(vf, pb.v, accB[dt], 0, 0, 0);
      }
    }
    __builtin_amdgcn_s_setprio(0);
    if (more) {
#pragma unroll
      for (int j = 0; j < 2; ++j) {
        *(bf16x8*)&Ks[cur ^ 1][srow + j*32][scol] = kreg[j];
        *(bf16x8*)&Vt[cur ^ 1][srow + j*32][scol] = vreg[j];
      }
      __syncthreads();
    }
  }
  // epilogue: reduce per-lane denominators once; lane owns q-col
  {
    float ls = lsA;
    ls += __shfl_xor(ls, 16);
    ls += __shfl_xor(ls, 32);
    const float inv = 1.0f / ls;
    size_t base = ((size_t)(b*2048 + qgA) << 10) + h*64;
#pragma unroll
    for (int dt = 0; dt < 4; ++dt) {
      uint2 pk;
      pk.x = cvt_pk_bf16(accA[dt][0] * inv, accA[dt][1] * inv);
      pk.y = cvt_pk_bf16(accA[dt][2] * inv, accA[dt][3] * inv);
      *(uint2*)&Yb[base + dt*16 + g*4] = pk;
    }
  }
  {
    float ls = lsB;
    ls += __shfl_xor(ls, 16);
    ls += __shfl_xor(ls, 32);
    const float inv = 1.0f / ls;
    size_t base = ((size_t)(b*2048 + qgB) << 10) + h*64;
#pragma unroll
    for (int dt = 0; dt < 4; ++dt) {
      uint2 pk;
      pk.x = cvt_pk_bf16(accB[dt][0] * inv, accB[dt][1] * inv);
      pk.y = cvt_pk_bf16(accB[dt][2] * inv, accB[dt][3] * inv);
      *(uint2*)&Yb[base + dt*16 + g*4] = pk;
    }
  }
}

extern "C" void kernel_launch(void* const* d_in, const int* in_sizes, int n_in,
                              void* d_out, int out_size, void* d_ws, size_t ws_size,
                              hipStream_t stream) {
  const float* x  = (const float*)d_in[0];
  const float* rc = (const float*)d_in[1];
  const float* rs = (const float*)d_in[2];
  // d_in[3] = attn_mask: pure causal -1e9, implemented analytically
  const float* Wq = (const float*)d_in[4];
  const float* Wk = (const float*)d_in[5];
  const float* Wv = (const float*)d_in[6];
  const float* Wo = (const float*)d_in[7];
  float* out = (float*)d_out;

  char* ws = (char*)d_ws;
  unsigned short* xb   = (unsigned short*)(ws);               // 4096x1024 bf16  (8 MB)
  unsigned short* Wcat = (unsigned short*)(ws + 8388608);     // 1536x1024 bf16  (3 MB)
  unsigned short* Wob  = (unsigned short*)(ws + 11534336);    // 1024x1024 bf16  (2 MB)
  unsigned short* Qb   = (unsigned short*)(ws + 38797312);    // 2x16x2048x64    (8 MB)
  unsigned short* Kb   = (unsigned short*)(ws + 47185920);    // 2x4x2048x64     (2 MB)
  unsigned short* Vb   = (unsigned short*)(ws + 49283072);    // 2x4x64x2048 ^T  (2 MB)
  unsigned short* Yb   = (unsigned short*)(ws + 51380224);    // 4096x1024 bf16  (8 MB)

  cvt_kernel<<<4096, 256, 0, stream>>>(x, xb, 1048576);
  cvt_w4<<<2560, 256, 0, stream>>>(Wq, Wk, Wv, Wo, Wcat, Wob);
  gemm_qkv_rope<<<dim3(12, 32), 256, 0, stream>>>(xb, Wcat, rc, rs, Qb, Kb, Vb);
  attn_kernel<<<dim3(16, 32), 256, 0, stream>>>(Qb, Kb, Vb, Yb);
  gemm_bt<<<dim3(8, 32), 256, 0, stream>>>(Yb, Wob, out, 4096, 1024, 1024);
}